// Round 1
// baseline (1060.602 us; speedup 1.0000x reference)
//
#include <hip/hip_runtime.h>

#define N_USERS 100000
#define N_ITEMS 40000
#define NN      140000          // N_NODES
#define N_EDGES 1000000
#define ALPHA   0.2f

// ---------------------------------------------------------------------------
// Copy user preference rows into interleaved X[NN][128] (img dims 0..63, txt 64..127)
__global__ void copy_pref(const float* __restrict__ imgp,
                          const float* __restrict__ txtp,
                          float* __restrict__ X)
{
    int tid = blockIdx.x * 256 + threadIdx.x;          // over N_USERS*32 float4s
    if (tid >= N_USERS * 32) return;
    int i  = tid >> 5;
    int c4 = tid & 31;
    float4 v;
    if (c4 < 16) v = *reinterpret_cast<const float4*>(&imgp[(size_t)i * 64 + c4 * 4]);
    else         v = *reinterpret_cast<const float4*>(&txtp[(size_t)i * 64 + (c4 - 16) * 4]);
    *reinterpret_cast<float4*>(&X[(size_t)i * 128 + c4 * 4]) = v;
}

// ---------------------------------------------------------------------------
// C[40000,64] = normalize(A[40000,K] @ W[K,64] + b), written into X rows N_USERS..,
// cols COLOFF..COLOFF+63. 1 wave per block, 64x64 tile, 8x8 register tile.
template<int K, int COLOFF>
__global__ __launch_bounds__(64)
void gemm_norm(const float* __restrict__ A, const float* __restrict__ W,
               const float* __restrict__ bias, float* __restrict__ X)
{
    __shared__ float At[32 * 68];      // [kk][r] transposed, pad 68 floats/row
    const int lane = threadIdx.x;
    const int cx   = lane & 7;         // cols cx*8 .. +7
    const int ry   = lane >> 3;        // rows ry*8 .. +7
    const int r0   = blockIdx.x * 64;

    float acc[8][8];
    #pragma unroll
    for (int i = 0; i < 8; i++)
        #pragma unroll
        for (int j = 0; j < 8; j++) acc[i][j] = 0.f;

    for (int k0 = 0; k0 < K; k0 += 32) {
        // stage A tile (64 rows x 32 k) transposed into LDS
        #pragma unroll
        for (int i = 0; i < 8; i++) {
            int q  = lane + i * 64;            // 0..511 float4 slots
            int r  = q >> 3;
            int ko = (q & 7) * 4;
            float4 v = *reinterpret_cast<const float4*>(&A[(size_t)(r0 + r) * K + k0 + ko]);
            At[(ko + 0) * 68 + r] = v.x;
            At[(ko + 1) * 68 + r] = v.y;
            At[(ko + 2) * 68 + r] = v.z;
            At[(ko + 3) * 68 + r] = v.w;
        }
        __syncthreads();
        #pragma unroll
        for (int kk = 0; kk < 32; kk++) {
            float4 a0 = *reinterpret_cast<const float4*>(&At[kk * 68 + ry * 8]);
            float4 a1 = *reinterpret_cast<const float4*>(&At[kk * 68 + ry * 8 + 4]);
            float4 w0 = *reinterpret_cast<const float4*>(&W[(size_t)(k0 + kk) * 64 + cx * 8]);
            float4 w1 = *reinterpret_cast<const float4*>(&W[(size_t)(k0 + kk) * 64 + cx * 8 + 4]);
            float a[8] = {a0.x, a0.y, a0.z, a0.w, a1.x, a1.y, a1.z, a1.w};
            float w[8] = {w0.x, w0.y, w0.z, w0.w, w1.x, w1.y, w1.z, w1.w};
            #pragma unroll
            for (int i = 0; i < 8; i++)
                #pragma unroll
                for (int j = 0; j < 8; j++)
                    acc[i][j] = fmaf(a[i], w[j], acc[i][j]);
        }
        __syncthreads();
    }

    float4 b0 = *reinterpret_cast<const float4*>(&bias[cx * 8]);
    float4 b1 = *reinterpret_cast<const float4*>(&bias[cx * 8 + 4]);
    float bb[8] = {b0.x, b0.y, b0.z, b0.w, b1.x, b1.y, b1.z, b1.w};

    #pragma unroll
    for (int i = 0; i < 8; i++) {
        float v[8];
        float ss = 0.f;
        #pragma unroll
        for (int j = 0; j < 8; j++) { v[j] = acc[i][j] + bb[j]; ss += v[j] * v[j]; }
        ss += __shfl_xor(ss, 1);
        ss += __shfl_xor(ss, 2);
        ss += __shfl_xor(ss, 4);
        float scale = 1.0f / fmaxf(sqrtf(ss), 1e-12f);
        int row = r0 + ry * 8 + i;
        float* dst = &X[(size_t)(N_USERS + row) * 128 + COLOFF + cx * 8];
        float4 o0 = make_float4(v[0] * scale, v[1] * scale, v[2] * scale, v[3] * scale);
        float4 o1 = make_float4(v[4] * scale, v[5] * scale, v[6] * scale, v[7] * scale);
        *reinterpret_cast<float4*>(dst)     = o0;
        *reinterpret_cast<float4*>(dst + 4) = o1;
    }
}

// ---------------------------------------------------------------------------
// CSR build
__global__ void hist_kernel(const int* __restrict__ ei, int* __restrict__ deg)
{
    int e = blockIdx.x * 256 + threadIdx.x;
    if (e < N_EDGES) atomicAdd(&deg[ei[N_EDGES + e]], 1);
}

__global__ void scan1(const int* __restrict__ deg, int* __restrict__ row_ptr,
                      int* __restrict__ blockSums)
{
    __shared__ int ts[256];
    int t = threadIdx.x, b = blockIdx.x;
    int base = b * 1024 + t * 4;
    int v[4]; int s = 0;
    #pragma unroll
    for (int j = 0; j < 4; j++) {
        v[j] = (base + j < NN) ? deg[base + j] : 0;
        s += v[j];
    }
    ts[t] = s;
    __syncthreads();
    for (int off = 1; off < 256; off <<= 1) {
        int x = (t >= off) ? ts[t - off] : 0;
        __syncthreads();
        ts[t] += x;
        __syncthreads();
    }
    int excl = ts[t] - s;
    int run = excl;
    #pragma unroll
    for (int j = 0; j < 4; j++) {
        if (base + j < NN) row_ptr[base + j] = run;
        run += v[j];
    }
    if (t == 255) blockSums[b] = ts[255];
}

__global__ void scan2(int* __restrict__ blockSums, int* __restrict__ row_ptr)
{
    __shared__ int ts[256];
    int t = threadIdx.x;
    int v = (t < 137) ? blockSums[t] : 0;
    ts[t] = v;
    __syncthreads();
    for (int off = 1; off < 256; off <<= 1) {
        int x = (t >= off) ? ts[t - off] : 0;
        __syncthreads();
        ts[t] += x;
        __syncthreads();
    }
    if (t < 137) blockSums[t] = ts[t] - v;   // exclusive
    if (t == 0) row_ptr[NN] = N_EDGES;
}

__global__ void scan3(int* __restrict__ row_ptr, int* __restrict__ cursor,
                      const int* __restrict__ blockSums)
{
    int t = threadIdx.x, b = blockIdx.x;
    int off = blockSums[b];
    int base = b * 1024 + t * 4;
    #pragma unroll
    for (int j = 0; j < 4; j++) {
        int idx = base + j;
        if (idx < NN) {
            int r = row_ptr[idx] + off;
            row_ptr[idx] = r;
            cursor[idx]  = r;
        }
    }
}

__global__ void fill_kernel(const int* __restrict__ ei, const float* __restrict__ ew,
                            int* __restrict__ cursor, int* __restrict__ esrc,
                            float* __restrict__ ewt)
{
    int e = blockIdx.x * 256 + threadIdx.x;
    if (e >= N_EDGES) return;
    int s = ei[e];
    int d = ei[N_EDGES + e];
    int p = atomicAdd(&cursor[d], 1);
    esrc[p] = s;
    ewt[p]  = ew[e];
}

// ---------------------------------------------------------------------------
// Gather-based propagation: one wave per destination node, lane owns 2 of 128 dims.
// FINAL=true writes split [2][NN][64] layout.
template<bool FINAL>
__global__ __launch_bounds__(256)
void propagate(const float* __restrict__ Xin, const int* __restrict__ row_ptr,
               const int* __restrict__ esrc, const float* __restrict__ ewt,
               float* __restrict__ out)
{
    int wid  = threadIdx.x >> 6;
    int lane = threadIdx.x & 63;
    int node = blockIdx.x * 4 + wid;
    if (node >= NN) return;
    int e0 = row_ptr[node];
    int e1 = row_ptr[node + 1];
    float2 acc = make_float2(0.f, 0.f);
    for (int e = e0; e < e1; e++) {
        int   s = esrc[e];
        float w = ewt[e];
        float2 v = *reinterpret_cast<const float2*>(&Xin[(size_t)s * 128 + lane * 2]);
        acc.x = fmaf(w, v.x, acc.x);
        acc.y = fmaf(w, v.y, acc.y);
    }
    float2 xs = *reinterpret_cast<const float2*>(&Xin[(size_t)node * 128 + lane * 2]);
    acc.x += ALPHA * xs.x;
    acc.y += ALPHA * xs.y;
    if (!FINAL) {
        *reinterpret_cast<float2*>(&out[(size_t)node * 128 + lane * 2]) = acc;
    } else {
        int d = lane * 2;
        float* dst = (d < 64) ? &out[(size_t)node * 64 + d]
                              : &out[(size_t)NN * 64 + (size_t)node * 64 + (d - 64)];
        *reinterpret_cast<float2*>(dst) = acc;
    }
}

// ---------------------------------------------------------------------------
extern "C" void kernel_launch(void* const* d_in, const int* in_sizes, int n_in,
                              void* d_out, int out_size, void* d_ws, size_t ws_size,
                              hipStream_t stream)
{
    const int*   ei       = (const int*)d_in[0];
    const float* ew       = (const float*)d_in[1];
    const float* img_feat = (const float*)d_in[2];
    const float* txt_feat = (const float*)d_in[3];
    const float* img_w    = (const float*)d_in[4];
    const float* img_b    = (const float*)d_in[5];
    const float* txt_w    = (const float*)d_in[6];
    const float* txt_b    = (const float*)d_in[7];
    const float* img_pref = (const float*)d_in[8];
    const float* txt_pref = (const float*)d_in[9];
    float* out = (float*)d_out;

    const size_t XBYTES = (size_t)NN * 128 * 4;
    char* ws = (char*)d_ws;
    size_t off = 0;
    auto alloc = [&](size_t bytes) -> void* {
        void* p = ws + off;
        off = (off + bytes + 255) & ~(size_t)255;
        return p;
    };
    float* Xa      = (float*)alloc(XBYTES);
    int*   deg     = (int*)alloc((size_t)NN * 4);
    int*   row_ptr = (int*)alloc((size_t)(NN + 1) * 4);
    int*   cursor  = (int*)alloc((size_t)NN * 4);
    int*   esrc    = (int*)alloc((size_t)N_EDGES * 4);
    float* ewt     = (float*)alloc((size_t)N_EDGES * 4);
    int*   bsums   = (int*)alloc(256 * 4);
    bool haveXb = (off + XBYTES) <= ws_size;
    float* Xb = haveXb ? (float*)alloc(XBYTES) : out;

    hipMemsetAsync(deg, 0, (size_t)NN * 4, stream);

    copy_pref<<<12500, 256, 0, stream>>>(img_pref, txt_pref, Xa);
    gemm_norm<2048, 0 ><<<625, 64, 0, stream>>>(img_feat, img_w, img_b, Xa);
    gemm_norm< 384, 64><<<625, 64, 0, stream>>>(txt_feat, txt_w, txt_b, Xa);

    hist_kernel<<<3907, 256, 0, stream>>>(ei, deg);
    scan1<<<137, 256, 0, stream>>>(deg, row_ptr, bsums);
    scan2<<<1, 256, 0, stream>>>(bsums, row_ptr);
    scan3<<<137, 256, 0, stream>>>(row_ptr, cursor, bsums);
    fill_kernel<<<3907, 256, 0, stream>>>(ei, ew, cursor, esrc, ewt);

    propagate<false><<<35000, 256, 0, stream>>>(Xa, row_ptr, esrc, ewt, Xb);
    if (haveXb) {
        propagate<true><<<35000, 256, 0, stream>>>(Xb, row_ptr, esrc, ewt, out);
    } else {
        propagate<true><<<35000, 256, 0, stream>>>(Xb, row_ptr, esrc, ewt, Xa);
        hipMemcpyAsync(out, Xa, XBYTES, hipMemcpyDeviceToDevice, stream);
    }
}

// Round 2
// 655.376 us; speedup vs baseline: 1.6183x; 1.6183x over previous
//
#include <hip/hip_runtime.h>

#define N_USERS 100000
#define N_ITEMS 40000
#define NN      140000          // N_NODES
#define N_EDGES 1000000
#define ALPHA   0.2f

// ---------------------------------------------------------------------------
// Copy user preference rows into interleaved X[NN][128] (img dims 0..63, txt 64..127)
__global__ void copy_pref(const float* __restrict__ imgp,
                          const float* __restrict__ txtp,
                          float* __restrict__ X)
{
    int tid = blockIdx.x * 256 + threadIdx.x;          // over N_USERS*32 float4s
    if (tid >= N_USERS * 32) return;
    int i  = tid >> 5;
    int c4 = tid & 31;
    float4 v;
    if (c4 < 16) v = *reinterpret_cast<const float4*>(&imgp[(size_t)i * 64 + c4 * 4]);
    else         v = *reinterpret_cast<const float4*>(&txtp[(size_t)i * 64 + (c4 - 16) * 4]);
    *reinterpret_cast<float4*>(&X[(size_t)i * 128 + c4 * 4]) = v;
}

// ---------------------------------------------------------------------------
// C[40000,64] = normalize(A[40000,K] @ W[K,64] + b) -> X rows N_USERS.., cols COLOFF..
// 256 threads = 4 waves; 64x64 tile; K split across waves; pairwise LDS reduce.
template<int K, int COLOFF>
__global__ __launch_bounds__(256, 2)
void gemm_norm(const float* __restrict__ A, const float* __restrict__ W,
               const float* __restrict__ bias, float* __restrict__ X)
{
    constexpr int KW    = K / 4;      // per-wave K range
    constexpr int STEPS = KW / 32;    // k-steps of 32 per wave
    __shared__ float lds[8704];       // staging [4][32][64] (8192 f) / red 2x[64][68]

    const int t    = threadIdx.x;
    const int wid  = t >> 6;
    const int lane = t & 63;
    const int cx   = lane & 7;        // cols cx*8..+7
    const int ry   = lane >> 3;       // rows ry*8..+7
    const int r0   = blockIdx.x * 64;

    float acc[8][8];
    #pragma unroll
    for (int i = 0; i < 8; i++)
        #pragma unroll
        for (int j = 0; j < 8; j++) acc[i][j] = 0.f;

    const float* Wp = W + (size_t)(wid * KW) * 64 + cx * 8;

    for (int s = 0; s < STEPS; ++s) {
        // stage A[r0..+64][4 chunks of 32 k] into lds[c][kk][row]
        #pragma unroll
        for (int i = 0; i < 8; ++i) {
            int q   = t + i * 256;      // 0..2047 float4 slots
            int c   = q >> 9;
            int row = (q >> 3) & 63;
            int kf4 = q & 7;
            int gk  = c * KW + s * 32 + kf4 * 4;
            float4 v = *reinterpret_cast<const float4*>(&A[(size_t)(r0 + row) * K + gk]);
            float* dst = &lds[c * 2048 + (kf4 * 4) * 64 + row];
            dst[0] = v.x; dst[64] = v.y; dst[128] = v.z; dst[192] = v.w;
        }
        __syncthreads();
        const float* At = &lds[wid * 2048];
        #pragma unroll
        for (int kk = 0; kk < 32; ++kk) {
            float4 a0 = *reinterpret_cast<const float4*>(&At[kk * 64 + ry * 8]);
            float4 a1 = *reinterpret_cast<const float4*>(&At[kk * 64 + ry * 8 + 4]);
            const float* wrow = Wp + (size_t)(s * 32 + kk) * 64;
            float4 w0 = *reinterpret_cast<const float4*>(&wrow[0]);
            float4 w1 = *reinterpret_cast<const float4*>(&wrow[4]);
            float a[8] = {a0.x, a0.y, a0.z, a0.w, a1.x, a1.y, a1.z, a1.w};
            float w[8] = {w0.x, w0.y, w0.z, w0.w, w1.x, w1.y, w1.z, w1.w};
            #pragma unroll
            for (int i = 0; i < 8; i++)
                #pragma unroll
                for (int j = 0; j < 8; j++)
                    acc[i][j] = fmaf(a[i], w[j], acc[i][j]);
        }
        __syncthreads();
    }

    // pairwise cross-wave reduction through LDS (stride 68 rows, 16B aligned)
    float* red0 = lds;
    float* red1 = lds + 64 * 68;
    if (wid >= 2) {
        float* r = (wid == 2) ? red0 : red1;
        #pragma unroll
        for (int i = 0; i < 8; ++i) {
            float* dst = &r[(ry * 8 + i) * 68 + cx * 8];
            *reinterpret_cast<float4*>(dst)     = make_float4(acc[i][0], acc[i][1], acc[i][2], acc[i][3]);
            *reinterpret_cast<float4*>(dst + 4) = make_float4(acc[i][4], acc[i][5], acc[i][6], acc[i][7]);
        }
    }
    __syncthreads();
    if (wid < 2) {
        float* r = (wid == 0) ? red0 : red1;
        #pragma unroll
        for (int i = 0; i < 8; ++i) {
            const float* src = &r[(ry * 8 + i) * 68 + cx * 8];
            float4 p0 = *reinterpret_cast<const float4*>(src);
            float4 p1 = *reinterpret_cast<const float4*>(src + 4);
            acc[i][0] += p0.x; acc[i][1] += p0.y; acc[i][2] += p0.z; acc[i][3] += p0.w;
            acc[i][4] += p1.x; acc[i][5] += p1.y; acc[i][6] += p1.z; acc[i][7] += p1.w;
        }
    }
    __syncthreads();
    if (wid == 1) {
        #pragma unroll
        for (int i = 0; i < 8; ++i) {
            float* dst = &red0[(ry * 8 + i) * 68 + cx * 8];
            *reinterpret_cast<float4*>(dst)     = make_float4(acc[i][0], acc[i][1], acc[i][2], acc[i][3]);
            *reinterpret_cast<float4*>(dst + 4) = make_float4(acc[i][4], acc[i][5], acc[i][6], acc[i][7]);
        }
    }
    __syncthreads();
    if (wid == 0) {
        #pragma unroll
        for (int i = 0; i < 8; ++i) {
            const float* src = &red0[(ry * 8 + i) * 68 + cx * 8];
            float4 p0 = *reinterpret_cast<const float4*>(src);
            float4 p1 = *reinterpret_cast<const float4*>(src + 4);
            acc[i][0] += p0.x; acc[i][1] += p0.y; acc[i][2] += p0.z; acc[i][3] += p0.w;
            acc[i][4] += p1.x; acc[i][5] += p1.y; acc[i][6] += p1.z; acc[i][7] += p1.w;
        }
        float4 b0 = *reinterpret_cast<const float4*>(&bias[cx * 8]);
        float4 b1 = *reinterpret_cast<const float4*>(&bias[cx * 8 + 4]);
        float bb[8] = {b0.x, b0.y, b0.z, b0.w, b1.x, b1.y, b1.z, b1.w};
        #pragma unroll
        for (int i = 0; i < 8; ++i) {
            float v[8];
            float ss = 0.f;
            #pragma unroll
            for (int j = 0; j < 8; j++) { v[j] = acc[i][j] + bb[j]; ss += v[j] * v[j]; }
            ss += __shfl_xor(ss, 1);
            ss += __shfl_xor(ss, 2);
            ss += __shfl_xor(ss, 4);
            float scale = 1.0f / fmaxf(sqrtf(ss), 1e-12f);
            int row = r0 + ry * 8 + i;
            float* dst = &X[(size_t)(N_USERS + row) * 128 + COLOFF + cx * 8];
            *reinterpret_cast<float4*>(dst)     = make_float4(v[0] * scale, v[1] * scale, v[2] * scale, v[3] * scale);
            *reinterpret_cast<float4*>(dst + 4) = make_float4(v[4] * scale, v[5] * scale, v[6] * scale, v[7] * scale);
        }
    }
}

// ---------------------------------------------------------------------------
// CSR build
__global__ void hist_kernel(const int* __restrict__ ei, int* __restrict__ deg)
{
    int e = blockIdx.x * 256 + threadIdx.x;
    if (e < N_EDGES) atomicAdd(&deg[ei[N_EDGES + e]], 1);
}

__global__ void scan1(const int* __restrict__ deg, int* __restrict__ row_ptr,
                      int* __restrict__ blockSums)
{
    __shared__ int ts[256];
    int t = threadIdx.x, b = blockIdx.x;
    int base = b * 1024 + t * 4;
    int v[4]; int s = 0;
    #pragma unroll
    for (int j = 0; j < 4; j++) {
        v[j] = (base + j < NN) ? deg[base + j] : 0;
        s += v[j];
    }
    ts[t] = s;
    __syncthreads();
    for (int off = 1; off < 256; off <<= 1) {
        int x = (t >= off) ? ts[t - off] : 0;
        __syncthreads();
        ts[t] += x;
        __syncthreads();
    }
    int excl = ts[t] - s;
    int run = excl;
    #pragma unroll
    for (int j = 0; j < 4; j++) {
        if (base + j < NN) row_ptr[base + j] = run;
        run += v[j];
    }
    if (t == 255) blockSums[b] = ts[255];
}

__global__ void scan2(int* __restrict__ blockSums, int* __restrict__ row_ptr)
{
    __shared__ int ts[256];
    int t = threadIdx.x;
    int v = (t < 137) ? blockSums[t] : 0;
    ts[t] = v;
    __syncthreads();
    for (int off = 1; off < 256; off <<= 1) {
        int x = (t >= off) ? ts[t - off] : 0;
        __syncthreads();
        ts[t] += x;
        __syncthreads();
    }
    if (t < 137) blockSums[t] = ts[t] - v;   // exclusive
    if (t == 0) row_ptr[NN] = N_EDGES;
}

__global__ void scan3(int* __restrict__ row_ptr, int* __restrict__ cursor,
                      const int* __restrict__ blockSums)
{
    int t = threadIdx.x, b = blockIdx.x;
    int off = blockSums[b];
    int base = b * 1024 + t * 4;
    #pragma unroll
    for (int j = 0; j < 4; j++) {
        int idx = base + j;
        if (idx < NN) {
            int r = row_ptr[idx] + off;
            row_ptr[idx] = r;
            cursor[idx]  = r;
        }
    }
}

__global__ void fill_kernel(const int* __restrict__ ei, const float* __restrict__ ew,
                            int* __restrict__ cursor, int* __restrict__ esrc,
                            float* __restrict__ ewt)
{
    int e = blockIdx.x * 256 + threadIdx.x;
    if (e >= N_EDGES) return;
    int s = ei[e];
    int d = ei[N_EDGES + e];
    int p = atomicAdd(&cursor[d], 1);
    esrc[p] = s;
    ewt[p]  = ew[e];
}

// ---------------------------------------------------------------------------
// Gather-based propagation: one wave per destination node, lane owns 2 of 128 dims.
// FINAL=true writes split [2][NN][64] layout.
template<bool FINAL>
__global__ __launch_bounds__(256)
void propagate(const float* __restrict__ Xin, const int* __restrict__ row_ptr,
               const int* __restrict__ esrc, const float* __restrict__ ewt,
               float* __restrict__ out)
{
    int wid  = threadIdx.x >> 6;
    int lane = threadIdx.x & 63;
    int node = blockIdx.x * 4 + wid;
    if (node >= NN) return;
    int e0 = row_ptr[node];
    int e1 = row_ptr[node + 1];
    float2 acc = make_float2(0.f, 0.f);
    int e = e0;
    for (; e + 1 < e1; e += 2) {
        int   s0 = esrc[e];
        int   s1 = esrc[e + 1];
        float w0 = ewt[e];
        float w1 = ewt[e + 1];
        float2 v0 = *reinterpret_cast<const float2*>(&Xin[(size_t)s0 * 128 + lane * 2]);
        float2 v1 = *reinterpret_cast<const float2*>(&Xin[(size_t)s1 * 128 + lane * 2]);
        acc.x = fmaf(w0, v0.x, acc.x);
        acc.y = fmaf(w0, v0.y, acc.y);
        acc.x = fmaf(w1, v1.x, acc.x);
        acc.y = fmaf(w1, v1.y, acc.y);
    }
    if (e < e1) {
        int   s0 = esrc[e];
        float w0 = ewt[e];
        float2 v0 = *reinterpret_cast<const float2*>(&Xin[(size_t)s0 * 128 + lane * 2]);
        acc.x = fmaf(w0, v0.x, acc.x);
        acc.y = fmaf(w0, v0.y, acc.y);
    }
    float2 xs = *reinterpret_cast<const float2*>(&Xin[(size_t)node * 128 + lane * 2]);
    acc.x += ALPHA * xs.x;
    acc.y += ALPHA * xs.y;
    if (!FINAL) {
        *reinterpret_cast<float2*>(&out[(size_t)node * 128 + lane * 2]) = acc;
    } else {
        int d = lane * 2;
        float* dst = (d < 64) ? &out[(size_t)node * 64 + d]
                              : &out[(size_t)NN * 64 + (size_t)node * 64 + (d - 64)];
        *reinterpret_cast<float2*>(dst) = acc;
    }
}

// ---------------------------------------------------------------------------
extern "C" void kernel_launch(void* const* d_in, const int* in_sizes, int n_in,
                              void* d_out, int out_size, void* d_ws, size_t ws_size,
                              hipStream_t stream)
{
    const int*   ei       = (const int*)d_in[0];
    const float* ew       = (const float*)d_in[1];
    const float* img_feat = (const float*)d_in[2];
    const float* txt_feat = (const float*)d_in[3];
    const float* img_w    = (const float*)d_in[4];
    const float* img_b    = (const float*)d_in[5];
    const float* txt_w    = (const float*)d_in[6];
    const float* txt_b    = (const float*)d_in[7];
    const float* img_pref = (const float*)d_in[8];
    const float* txt_pref = (const float*)d_in[9];
    float* out = (float*)d_out;

    const size_t XBYTES = (size_t)NN * 128 * 4;
    char* ws = (char*)d_ws;
    size_t off = 0;
    auto alloc = [&](size_t bytes) -> void* {
        void* p = ws + off;
        off = (off + bytes + 255) & ~(size_t)255;
        return p;
    };
    float* Xa      = (float*)alloc(XBYTES);
    int*   deg     = (int*)alloc((size_t)NN * 4);
    int*   row_ptr = (int*)alloc((size_t)(NN + 1) * 4);
    int*   cursor  = (int*)alloc((size_t)NN * 4);
    int*   esrc    = (int*)alloc((size_t)N_EDGES * 4);
    float* ewt     = (float*)alloc((size_t)N_EDGES * 4);
    int*   bsums   = (int*)alloc(256 * 4);
    bool haveXb = (off + XBYTES) <= ws_size;
    float* Xb = haveXb ? (float*)alloc(XBYTES) : out;

    hipMemsetAsync(deg, 0, (size_t)NN * 4, stream);

    copy_pref<<<12500, 256, 0, stream>>>(img_pref, txt_pref, Xa);
    gemm_norm<2048, 0 ><<<625, 256, 0, stream>>>(img_feat, img_w, img_b, Xa);
    gemm_norm< 384, 64><<<625, 256, 0, stream>>>(txt_feat, txt_w, txt_b, Xa);

    hist_kernel<<<3907, 256, 0, stream>>>(ei, deg);
    scan1<<<137, 256, 0, stream>>>(deg, row_ptr, bsums);
    scan2<<<1, 256, 0, stream>>>(bsums, row_ptr);
    scan3<<<137, 256, 0, stream>>>(row_ptr, cursor, bsums);
    fill_kernel<<<3907, 256, 0, stream>>>(ei, ew, cursor, esrc, ewt);

    propagate<false><<<35000, 256, 0, stream>>>(Xa, row_ptr, esrc, ewt, Xb);
    if (haveXb) {
        propagate<true><<<35000, 256, 0, stream>>>(Xb, row_ptr, esrc, ewt, out);
    } else {
        propagate<true><<<35000, 256, 0, stream>>>(Xb, row_ptr, esrc, ewt, Xa);
        hipMemcpyAsync(out, Xa, XBYTES, hipMemcpyDeviceToDevice, stream);
    }
}

// Round 3
// 633.552 us; speedup vs baseline: 1.6741x; 1.0344x over previous
//
#include <hip/hip_runtime.h>

#define N_USERS 100000
#define N_ITEMS 40000
#define NN      140000          // N_NODES
#define N_EDGES 1000000
#define ALPHA   0.2f

// ---------------------------------------------------------------------------
// Copy user preference rows into interleaved X[NN][128] (img dims 0..63, txt 64..127)
__global__ void copy_pref(const float* __restrict__ imgp,
                          const float* __restrict__ txtp,
                          float* __restrict__ X)
{
    int tid = blockIdx.x * 256 + threadIdx.x;          // over N_USERS*32 float4s
    if (tid >= N_USERS * 32) return;
    int i  = tid >> 5;
    int c4 = tid & 31;
    float4 v;
    if (c4 < 16) v = *reinterpret_cast<const float4*>(&imgp[(size_t)i * 64 + c4 * 4]);
    else         v = *reinterpret_cast<const float4*>(&txtp[(size_t)i * 64 + (c4 - 16) * 4]);
    *reinterpret_cast<float4*>(&X[(size_t)i * 128 + c4 * 4]) = v;
}

// ---------------------------------------------------------------------------
// Partial GEMM: P[chunk][40000][64] += A[40000, kchunk] @ W[kchunk, 64]
// grid (625, NCHUNK); 256 threads = 4 waves; per block: 64 rows x KC k-range,
// KC split across the 4 waves; pairwise LDS reduce; wave 0 writes partial tile.
template<int K, int NCHUNK>
__global__ __launch_bounds__(256, 4)
void gemm_part(const float* __restrict__ A, const float* __restrict__ W,
               float* __restrict__ P)
{
    constexpr int KC    = K / NCHUNK;   // k per block
    constexpr int KW    = KC / 4;       // k per wave
    constexpr int STEPS = KW / 32;      // k-steps of 32 per wave
    __shared__ float lds[4 * 32 * 68];  // staging [4][32 kk][68 pad] = 34816 B

    const int t    = threadIdx.x;
    const int wid  = t >> 6;
    const int lane = t & 63;
    const int cx   = lane & 7;          // cols cx*8..+7
    const int ry   = lane >> 3;         // rows ry*8..+7
    const int r0   = blockIdx.x * 64;
    const int kb0  = blockIdx.y * KC;

    float acc[8][8];
    #pragma unroll
    for (int i = 0; i < 8; i++)
        #pragma unroll
        for (int j = 0; j < 8; j++) acc[i][j] = 0.f;

    const float* Wp = W + (size_t)(kb0 + wid * KW) * 64 + cx * 8;

    for (int s = 0; s < STEPS; ++s) {
        // stage A[r0..+64] for all 4 waves' current 32-k slices, [cc][kk][row] pad 68
        #pragma unroll
        for (int i = 0; i < 8; ++i) {
            int q   = t + i * 256;      // 0..2047 float4 slots
            int cc  = q >> 9;
            int row = (q >> 3) & 63;
            int kf4 = q & 7;
            int gk  = kb0 + cc * KW + s * 32 + kf4 * 4;
            float4 v = *reinterpret_cast<const float4*>(&A[(size_t)(r0 + row) * K + gk]);
            float* dst = &lds[cc * 2176 + (kf4 * 4) * 68 + row];
            dst[0] = v.x; dst[68] = v.y; dst[136] = v.z; dst[204] = v.w;
        }
        __syncthreads();
        const float* At = &lds[wid * 2176];
        #pragma unroll
        for (int kk = 0; kk < 32; ++kk) {
            float4 a0 = *reinterpret_cast<const float4*>(&At[kk * 68 + ry * 8]);
            float4 a1 = *reinterpret_cast<const float4*>(&At[kk * 68 + ry * 8 + 4]);
            const float* wrow = Wp + (size_t)(s * 32 + kk) * 64;
            float4 w0 = *reinterpret_cast<const float4*>(&wrow[0]);
            float4 w1 = *reinterpret_cast<const float4*>(&wrow[4]);
            float a[8] = {a0.x, a0.y, a0.z, a0.w, a1.x, a1.y, a1.z, a1.w};
            float w[8] = {w0.x, w0.y, w0.z, w0.w, w1.x, w1.y, w1.z, w1.w};
            #pragma unroll
            for (int i = 0; i < 8; i++)
                #pragma unroll
                for (int j = 0; j < 8; j++)
                    acc[i][j] = fmaf(a[i], w[j], acc[i][j]);
        }
        __syncthreads();
    }

    // pairwise cross-wave reduction through LDS (row stride 68, 16B aligned)
    float* red0 = lds;
    float* red1 = lds + 64 * 68;
    if (wid >= 2) {
        float* r = (wid == 2) ? red0 : red1;
        #pragma unroll
        for (int i = 0; i < 8; ++i) {
            float* dst = &r[(ry * 8 + i) * 68 + cx * 8];
            *reinterpret_cast<float4*>(dst)     = make_float4(acc[i][0], acc[i][1], acc[i][2], acc[i][3]);
            *reinterpret_cast<float4*>(dst + 4) = make_float4(acc[i][4], acc[i][5], acc[i][6], acc[i][7]);
        }
    }
    __syncthreads();
    if (wid < 2) {
        float* r = (wid == 0) ? red0 : red1;
        #pragma unroll
        for (int i = 0; i < 8; ++i) {
            const float* src = &r[(ry * 8 + i) * 68 + cx * 8];
            float4 p0 = *reinterpret_cast<const float4*>(src);
            float4 p1 = *reinterpret_cast<const float4*>(src + 4);
            acc[i][0] += p0.x; acc[i][1] += p0.y; acc[i][2] += p0.z; acc[i][3] += p0.w;
            acc[i][4] += p1.x; acc[i][5] += p1.y; acc[i][6] += p1.z; acc[i][7] += p1.w;
        }
    }
    __syncthreads();
    if (wid == 1) {
        #pragma unroll
        for (int i = 0; i < 8; ++i) {
            float* dst = &red0[(ry * 8 + i) * 68 + cx * 8];
            *reinterpret_cast<float4*>(dst)     = make_float4(acc[i][0], acc[i][1], acc[i][2], acc[i][3]);
            *reinterpret_cast<float4*>(dst + 4) = make_float4(acc[i][4], acc[i][5], acc[i][6], acc[i][7]);
        }
    }
    __syncthreads();
    if (wid == 0) {
        #pragma unroll
        for (int i = 0; i < 8; ++i) {
            const float* src = &red0[(ry * 8 + i) * 68 + cx * 8];
            float4 p0 = *reinterpret_cast<const float4*>(src);
            float4 p1 = *reinterpret_cast<const float4*>(src + 4);
            acc[i][0] += p0.x; acc[i][1] += p0.y; acc[i][2] += p0.z; acc[i][3] += p0.w;
            acc[i][4] += p1.x; acc[i][5] += p1.y; acc[i][6] += p1.z; acc[i][7] += p1.w;
        }
        #pragma unroll
        for (int i = 0; i < 8; ++i) {
            int row = r0 + ry * 8 + i;
            float* dst = &P[((size_t)blockIdx.y * 40000 + row) * 64 + cx * 8];
            *reinterpret_cast<float4*>(dst)     = make_float4(acc[i][0], acc[i][1], acc[i][2], acc[i][3]);
            *reinterpret_cast<float4*>(dst + 4) = make_float4(acc[i][4], acc[i][5], acc[i][6], acc[i][7]);
        }
    }
}

// ---------------------------------------------------------------------------
// Sum NP partials + bias, row-L2-normalize, write into X cols COLOFF..
// One wave per row; 4 waves per block; grid 10000.
template<int NP, int COLOFF>
__global__ __launch_bounds__(256)
void reduce_norm(const float* __restrict__ P, const float* __restrict__ bias,
                 float* __restrict__ X)
{
    int wid  = threadIdx.x >> 6;
    int lane = threadIdx.x & 63;
    int row  = blockIdx.x * 4 + wid;
    float v = 0.f;
    #pragma unroll
    for (int p = 0; p < NP; ++p)
        v += P[((size_t)p * 40000 + row) * 64 + lane];
    v += bias[lane];
    float ss = v * v;
    ss += __shfl_xor(ss, 1);
    ss += __shfl_xor(ss, 2);
    ss += __shfl_xor(ss, 4);
    ss += __shfl_xor(ss, 8);
    ss += __shfl_xor(ss, 16);
    ss += __shfl_xor(ss, 32);
    float scale = 1.0f / fmaxf(sqrtf(ss), 1e-12f);
    X[(size_t)(N_USERS + row) * 128 + COLOFF + lane] = v * scale;
}

// ---------------------------------------------------------------------------
// CSR build
__global__ void hist_kernel(const int* __restrict__ ei, int* __restrict__ deg)
{
    int e = blockIdx.x * 256 + threadIdx.x;
    if (e < N_EDGES) atomicAdd(&deg[ei[N_EDGES + e]], 1);
}

__global__ void scan1(const int* __restrict__ deg, int* __restrict__ row_ptr,
                      int* __restrict__ blockSums)
{
    __shared__ int ts[256];
    int t = threadIdx.x, b = blockIdx.x;
    int base = b * 1024 + t * 4;
    int v[4]; int s = 0;
    #pragma unroll
    for (int j = 0; j < 4; j++) {
        v[j] = (base + j < NN) ? deg[base + j] : 0;
        s += v[j];
    }
    ts[t] = s;
    __syncthreads();
    for (int off = 1; off < 256; off <<= 1) {
        int x = (t >= off) ? ts[t - off] : 0;
        __syncthreads();
        ts[t] += x;
        __syncthreads();
    }
    int excl = ts[t] - s;
    int run = excl;
    #pragma unroll
    for (int j = 0; j < 4; j++) {
        if (base + j < NN) row_ptr[base + j] = run;
        run += v[j];
    }
    if (t == 255) blockSums[b] = ts[255];
}

__global__ void scan2(int* __restrict__ blockSums, int* __restrict__ row_ptr)
{
    __shared__ int ts[256];
    int t = threadIdx.x;
    int v = (t < 137) ? blockSums[t] : 0;
    ts[t] = v;
    __syncthreads();
    for (int off = 1; off < 256; off <<= 1) {
        int x = (t >= off) ? ts[t - off] : 0;
        __syncthreads();
        ts[t] += x;
        __syncthreads();
    }
    if (t < 137) blockSums[t] = ts[t] - v;   // exclusive
    if (t == 0) row_ptr[NN] = N_EDGES;
}

__global__ void scan3(int* __restrict__ row_ptr, int* __restrict__ cursor,
                      const int* __restrict__ blockSums)
{
    int t = threadIdx.x, b = blockIdx.x;
    int off = blockSums[b];
    int base = b * 1024 + t * 4;
    #pragma unroll
    for (int j = 0; j < 4; j++) {
        int idx = base + j;
        if (idx < NN) {
            int r = row_ptr[idx] + off;
            row_ptr[idx] = r;
            cursor[idx]  = r;
        }
    }
}

__global__ void fill_kernel(const int* __restrict__ ei, const float* __restrict__ ew,
                            int* __restrict__ cursor, int* __restrict__ esrc,
                            float* __restrict__ ewt)
{
    int e = blockIdx.x * 256 + threadIdx.x;
    if (e >= N_EDGES) return;
    int s = ei[e];
    int d = ei[N_EDGES + e];
    int p = atomicAdd(&cursor[d], 1);
    esrc[p] = s;
    ewt[p]  = ew[e];
}

// ---------------------------------------------------------------------------
// Gather-based propagation: one wave per destination node, lane owns 2 of 128 dims.
// FINAL=true writes split [2][NN][64] layout.
template<bool FINAL>
__global__ __launch_bounds__(256)
void propagate(const float* __restrict__ Xin, const int* __restrict__ row_ptr,
               const int* __restrict__ esrc, const float* __restrict__ ewt,
               float* __restrict__ out)
{
    int wid  = threadIdx.x >> 6;
    int lane = threadIdx.x & 63;
    int node = blockIdx.x * 4 + wid;
    if (node >= NN) return;
    int e0 = row_ptr[node];
    int e1 = row_ptr[node + 1];
    float2 acc = make_float2(0.f, 0.f);
    int e = e0;
    for (; e + 1 < e1; e += 2) {
        int   s0 = esrc[e];
        int   s1 = esrc[e + 1];
        float w0 = ewt[e];
        float w1 = ewt[e + 1];
        float2 v0 = *reinterpret_cast<const float2*>(&Xin[(size_t)s0 * 128 + lane * 2]);
        float2 v1 = *reinterpret_cast<const float2*>(&Xin[(size_t)s1 * 128 + lane * 2]);
        acc.x = fmaf(w0, v0.x, acc.x);
        acc.y = fmaf(w0, v0.y, acc.y);
        acc.x = fmaf(w1, v1.x, acc.x);
        acc.y = fmaf(w1, v1.y, acc.y);
    }
    if (e < e1) {
        int   s0 = esrc[e];
        float w0 = ewt[e];
        float2 v0 = *reinterpret_cast<const float2*>(&Xin[(size_t)s0 * 128 + lane * 2]);
        acc.x = fmaf(w0, v0.x, acc.x);
        acc.y = fmaf(w0, v0.y, acc.y);
    }
    float2 xs = *reinterpret_cast<const float2*>(&Xin[(size_t)node * 128 + lane * 2]);
    acc.x += ALPHA * xs.x;
    acc.y += ALPHA * xs.y;
    if (!FINAL) {
        *reinterpret_cast<float2*>(&out[(size_t)node * 128 + lane * 2]) = acc;
    } else {
        int d = lane * 2;
        float* dst = (d < 64) ? &out[(size_t)node * 64 + d]
                              : &out[(size_t)NN * 64 + (size_t)node * 64 + (d - 64)];
        *reinterpret_cast<float2*>(dst) = acc;
    }
}

// ---------------------------------------------------------------------------
extern "C" void kernel_launch(void* const* d_in, const int* in_sizes, int n_in,
                              void* d_out, int out_size, void* d_ws, size_t ws_size,
                              hipStream_t stream)
{
    const int*   ei       = (const int*)d_in[0];
    const float* ew       = (const float*)d_in[1];
    const float* img_feat = (const float*)d_in[2];
    const float* txt_feat = (const float*)d_in[3];
    const float* img_w    = (const float*)d_in[4];
    const float* img_b    = (const float*)d_in[5];
    const float* txt_w    = (const float*)d_in[6];
    const float* txt_b    = (const float*)d_in[7];
    const float* img_pref = (const float*)d_in[8];
    const float* txt_pref = (const float*)d_in[9];
    float* out = (float*)d_out;

    const size_t XBYTES = (size_t)NN * 128 * 4;
    const size_t PBYTES = (size_t)4 * 40000 * 64 * 4;
    char* ws = (char*)d_ws;
    size_t off = 0;
    auto alloc = [&](size_t bytes) -> void* {
        void* p = ws + off;
        off = (off + bytes + 255) & ~(size_t)255;
        return p;
    };
    float* Xa      = (float*)alloc(XBYTES);
    int*   deg     = (int*)alloc((size_t)NN * 4);
    int*   row_ptr = (int*)alloc((size_t)(NN + 1) * 4);
    int*   cursor  = (int*)alloc((size_t)NN * 4);
    int*   esrc    = (int*)alloc((size_t)N_EDGES * 4);
    float* ewt     = (float*)alloc((size_t)N_EDGES * 4);
    int*   bsums   = (int*)alloc(256 * 4);
    bool haveP = (off + PBYTES) <= ws_size;
    float* P = haveP ? (float*)alloc(PBYTES) : out;   // out is consumed-before-propagate safe
    bool haveXb = (off + XBYTES) <= ws_size;
    float* Xb = haveXb ? (float*)alloc(XBYTES) : out;

    hipMemsetAsync(deg, 0, (size_t)NN * 4, stream);

    copy_pref<<<12500, 256, 0, stream>>>(img_pref, txt_pref, Xa);
    gemm_part<2048, 4><<<dim3(625, 4), 256, 0, stream>>>(img_feat, img_w, P);
    reduce_norm<4, 0><<<10000, 256, 0, stream>>>(P, img_b, Xa);
    gemm_part<384, 3><<<dim3(625, 3), 256, 0, stream>>>(txt_feat, txt_w, P);
    reduce_norm<3, 64><<<10000, 256, 0, stream>>>(P, txt_b, Xa);

    hist_kernel<<<3907, 256, 0, stream>>>(ei, deg);
    scan1<<<137, 256, 0, stream>>>(deg, row_ptr, bsums);
    scan2<<<1, 256, 0, stream>>>(bsums, row_ptr);
    scan3<<<137, 256, 0, stream>>>(row_ptr, cursor, bsums);
    fill_kernel<<<3907, 256, 0, stream>>>(ei, ew, cursor, esrc, ewt);

    propagate<false><<<35000, 256, 0, stream>>>(Xa, row_ptr, esrc, ewt, Xb);
    if (haveXb) {
        propagate<true><<<35000, 256, 0, stream>>>(Xb, row_ptr, esrc, ewt, out);
    } else {
        propagate<true><<<35000, 256, 0, stream>>>(Xb, row_ptr, esrc, ewt, Xa);
        hipMemcpyAsync(out, Xa, XBYTES, hipMemcpyDeviceToDevice, stream);
    }
}

// Round 4
// 566.968 us; speedup vs baseline: 1.8707x; 1.1174x over previous
//
#include <hip/hip_runtime.h>

#define N_USERS 100000
#define N_ITEMS 40000
#define NN      140000          // N_NODES
#define N_EDGES 1000000
#define ALPHA   0.2f

// ---------------------------------------------------------------------------
// Copy user preference rows into interleaved X[NN][128] (img dims 0..63, txt 64..127)
__global__ void copy_pref(const float* __restrict__ imgp,
                          const float* __restrict__ txtp,
                          float* __restrict__ X)
{
    int tid = blockIdx.x * 256 + threadIdx.x;          // over N_USERS*32 float4s
    if (tid >= N_USERS * 32) return;
    int i  = tid >> 5;
    int c4 = tid & 31;
    float4 v;
    if (c4 < 16) v = *reinterpret_cast<const float4*>(&imgp[(size_t)i * 64 + c4 * 4]);
    else         v = *reinterpret_cast<const float4*>(&txtp[(size_t)i * 64 + (c4 - 16) * 4]);
    *reinterpret_cast<float4*>(&X[(size_t)i * 128 + c4 * 4]) = v;
}

// ---------------------------------------------------------------------------
// Partial GEMM: P[chunk][40000][64] = A[40000, kchunk] @ W[kchunk, 64]
// grid (625, NCHUNK); 256 threads = 4 waves; KC split across 4 waves;
// register-staged (async) A pipeline: issue step s+1 loads under step s compute.
template<int K, int NCHUNK>
__global__ __launch_bounds__(256, 2)
void gemm_part(const float* __restrict__ A, const float* __restrict__ W,
               float* __restrict__ P)
{
    constexpr int KC    = K / NCHUNK;   // k per block
    constexpr int KW    = KC / 4;       // k per wave
    constexpr int STEPS = KW / 32;      // k-steps of 32 per wave
    __shared__ float lds[4 * 32 * 68];  // staging [4][32 kk][68 pad] = 34816 B

    const int t    = threadIdx.x;
    const int wid  = t >> 6;
    const int lane = t & 63;
    const int cx   = lane & 7;          // cols cx*8..+7
    const int ry   = lane >> 3;         // rows ry*8..+7
    const int r0   = blockIdx.x * 64;
    const int kb0  = blockIdx.y * KC;

    float acc[8][8];
    #pragma unroll
    for (int i = 0; i < 8; i++)
        #pragma unroll
        for (int j = 0; j < 8; j++) acc[i][j] = 0.f;

    const float* Wp = W + (size_t)(kb0 + wid * KW) * 64 + cx * 8;

    // per-thread staging slot (constant across steps)
    const int q_cc  = t >> 6;                 // reuse wid pattern? no: q layout below
    (void)q_cc;

    // thread t+i*256 slot decomposition (i=0..7): q = t + i*256
    //   cc = q>>9, row=(q>>3)&63, kf4=q&7
    float4 ra[8], rb[8];

    auto issue = [&](int s, float4* r) {
        #pragma unroll
        for (int i = 0; i < 8; ++i) {
            int q   = t + i * 256;
            int cc  = q >> 9;
            int row = (q >> 3) & 63;
            int kf4 = q & 7;
            int gk  = kb0 + cc * KW + s * 32 + kf4 * 4;
            r[i] = *reinterpret_cast<const float4*>(&A[(size_t)(r0 + row) * K + gk]);
        }
    };
    auto stage = [&](const float4* r) {
        #pragma unroll
        for (int i = 0; i < 8; ++i) {
            int q   = t + i * 256;
            int cc  = q >> 9;
            int row = (q >> 3) & 63;
            int kf4 = q & 7;
            float* dst = &lds[cc * 2176 + (kf4 * 4) * 68 + row];
            dst[0] = r[i].x; dst[68] = r[i].y; dst[136] = r[i].z; dst[204] = r[i].w;
        }
    };
    auto compute = [&](int s) {
        const float* At = &lds[wid * 2176];
        #pragma unroll
        for (int kk = 0; kk < 32; ++kk) {
            float4 a0 = *reinterpret_cast<const float4*>(&At[kk * 68 + ry * 8]);
            float4 a1 = *reinterpret_cast<const float4*>(&At[kk * 68 + ry * 8 + 4]);
            const float* wrow = Wp + (size_t)(s * 32 + kk) * 64;
            float4 w0 = *reinterpret_cast<const float4*>(&wrow[0]);
            float4 w1 = *reinterpret_cast<const float4*>(&wrow[4]);
            float a[8] = {a0.x, a0.y, a0.z, a0.w, a1.x, a1.y, a1.z, a1.w};
            float w[8] = {w0.x, w0.y, w0.z, w0.w, w1.x, w1.y, w1.z, w1.w};
            #pragma unroll
            for (int i = 0; i < 8; i++)
                #pragma unroll
                for (int j = 0; j < 8; j++)
                    acc[i][j] = fmaf(a[i], w[j], acc[i][j]);
        }
    };

    issue(0, ra);
    #pragma unroll
    for (int s = 0; s < STEPS; ++s) {
        if (s > 0) __syncthreads();           // prev step's LDS reads done
        if (s & 1) {
            stage(rb);
            if (s + 1 < STEPS) issue(s + 1, ra);
        } else {
            stage(ra);
            if (s + 1 < STEPS) issue(s + 1, rb);
        }
        __syncthreads();
        compute(s);
    }

    // pairwise cross-wave reduction through LDS (row stride 68, 16B aligned)
    __syncthreads();
    float* red0 = lds;
    float* red1 = lds + 64 * 68;
    if (wid >= 2) {
        float* r = (wid == 2) ? red0 : red1;
        #pragma unroll
        for (int i = 0; i < 8; ++i) {
            float* dst = &r[(ry * 8 + i) * 68 + cx * 8];
            *reinterpret_cast<float4*>(dst)     = make_float4(acc[i][0], acc[i][1], acc[i][2], acc[i][3]);
            *reinterpret_cast<float4*>(dst + 4) = make_float4(acc[i][4], acc[i][5], acc[i][6], acc[i][7]);
        }
    }
    __syncthreads();
    if (wid < 2) {
        float* r = (wid == 0) ? red0 : red1;
        #pragma unroll
        for (int i = 0; i < 8; ++i) {
            const float* src = &r[(ry * 8 + i) * 68 + cx * 8];
            float4 p0 = *reinterpret_cast<const float4*>(src);
            float4 p1 = *reinterpret_cast<const float4*>(src + 4);
            acc[i][0] += p0.x; acc[i][1] += p0.y; acc[i][2] += p0.z; acc[i][3] += p0.w;
            acc[i][4] += p1.x; acc[i][5] += p1.y; acc[i][6] += p1.z; acc[i][7] += p1.w;
        }
    }
    __syncthreads();
    if (wid == 1) {
        #pragma unroll
        for (int i = 0; i < 8; ++i) {
            float* dst = &red0[(ry * 8 + i) * 68 + cx * 8];
            *reinterpret_cast<float4*>(dst)     = make_float4(acc[i][0], acc[i][1], acc[i][2], acc[i][3]);
            *reinterpret_cast<float4*>(dst + 4) = make_float4(acc[i][4], acc[i][5], acc[i][6], acc[i][7]);
        }
    }
    __syncthreads();
    if (wid == 0) {
        #pragma unroll
        for (int i = 0; i < 8; ++i) {
            const float* src = &red0[(ry * 8 + i) * 68 + cx * 8];
            float4 p0 = *reinterpret_cast<const float4*>(src);
            float4 p1 = *reinterpret_cast<const float4*>(src + 4);
            acc[i][0] += p0.x; acc[i][1] += p0.y; acc[i][2] += p0.z; acc[i][3] += p0.w;
            acc[i][4] += p1.x; acc[i][5] += p1.y; acc[i][6] += p1.z; acc[i][7] += p1.w;
        }
        #pragma unroll
        for (int i = 0; i < 8; ++i) {
            int row = r0 + ry * 8 + i;
            float* dst = &P[((size_t)blockIdx.y * 40000 + row) * 64 + cx * 8];
            *reinterpret_cast<float4*>(dst)     = make_float4(acc[i][0], acc[i][1], acc[i][2], acc[i][3]);
            *reinterpret_cast<float4*>(dst + 4) = make_float4(acc[i][4], acc[i][5], acc[i][6], acc[i][7]);
        }
    }
}

// ---------------------------------------------------------------------------
// Sum NP partials + bias, row-L2-normalize, write into X cols COLOFF..
template<int NP, int COLOFF>
__global__ __launch_bounds__(256)
void reduce_norm(const float* __restrict__ P, const float* __restrict__ bias,
                 float* __restrict__ X)
{
    int wid  = threadIdx.x >> 6;
    int lane = threadIdx.x & 63;
    int row  = blockIdx.x * 4 + wid;
    float v = 0.f;
    #pragma unroll
    for (int p = 0; p < NP; ++p)
        v += P[((size_t)p * 40000 + row) * 64 + lane];
    v += bias[lane];
    float ss = v * v;
    ss += __shfl_xor(ss, 1);
    ss += __shfl_xor(ss, 2);
    ss += __shfl_xor(ss, 4);
    ss += __shfl_xor(ss, 8);
    ss += __shfl_xor(ss, 16);
    ss += __shfl_xor(ss, 32);
    float scale = 1.0f / fmaxf(sqrtf(ss), 1e-12f);
    X[(size_t)(N_USERS + row) * 128 + COLOFF + lane] = v * scale;
}

// ---------------------------------------------------------------------------
// CSR build
__global__ void hist_kernel(const int* __restrict__ ei, int* __restrict__ deg)
{
    int e = blockIdx.x * 256 + threadIdx.x;
    if (e < N_EDGES) atomicAdd(&deg[ei[N_EDGES + e]], 1);
}

__global__ void scan1(const int* __restrict__ deg, int* __restrict__ row_ptr,
                      int* __restrict__ blockSums)
{
    __shared__ int ts[256];
    int t = threadIdx.x, b = blockIdx.x;
    int base = b * 1024 + t * 4;
    int v[4]; int s = 0;
    #pragma unroll
    for (int j = 0; j < 4; j++) {
        v[j] = (base + j < NN) ? deg[base + j] : 0;
        s += v[j];
    }
    ts[t] = s;
    __syncthreads();
    for (int off = 1; off < 256; off <<= 1) {
        int x = (t >= off) ? ts[t - off] : 0;
        __syncthreads();
        ts[t] += x;
        __syncthreads();
    }
    int excl = ts[t] - s;
    int run = excl;
    #pragma unroll
    for (int j = 0; j < 4; j++) {
        if (base + j < NN) row_ptr[base + j] = run;
        run += v[j];
    }
    if (t == 255) blockSums[b] = ts[255];
}

__global__ void scan2(int* __restrict__ blockSums, int* __restrict__ row_ptr)
{
    __shared__ int ts[256];
    int t = threadIdx.x;
    int v = (t < 137) ? blockSums[t] : 0;
    ts[t] = v;
    __syncthreads();
    for (int off = 1; off < 256; off <<= 1) {
        int x = (t >= off) ? ts[t - off] : 0;
        __syncthreads();
        ts[t] += x;
        __syncthreads();
    }
    if (t < 137) blockSums[t] = ts[t] - v;   // exclusive
    if (t == 0) row_ptr[NN] = N_EDGES;
}

__global__ void scan3(int* __restrict__ row_ptr, int* __restrict__ cursor,
                      const int* __restrict__ blockSums)
{
    int t = threadIdx.x, b = blockIdx.x;
    int off = blockSums[b];
    int base = b * 1024 + t * 4;
    #pragma unroll
    for (int j = 0; j < 4; j++) {
        int idx = base + j;
        if (idx < NN) {
            int r = row_ptr[idx] + off;
            row_ptr[idx] = r;
            cursor[idx]  = r;
        }
    }
}

__global__ void fill_kernel(const int* __restrict__ ei, const float* __restrict__ ew,
                            int* __restrict__ cursor, int* __restrict__ esrc,
                            float* __restrict__ ewt)
{
    int e = blockIdx.x * 256 + threadIdx.x;
    if (e >= N_EDGES) return;
    int s = ei[e];
    int d = ei[N_EDGES + e];
    int p = atomicAdd(&cursor[d], 1);
    esrc[p] = s;
    ewt[p]  = ew[e];
}

// ---------------------------------------------------------------------------
// Gather-based propagation: one wave per destination node, lane owns 2 of 128 dims.
// FINAL=true writes split [2][NN][64] layout.
template<bool FINAL>
__global__ __launch_bounds__(256)
void propagate(const float* __restrict__ Xin, const int* __restrict__ row_ptr,
               const int* __restrict__ esrc, const float* __restrict__ ewt,
               float* __restrict__ out)
{
    int wid  = threadIdx.x >> 6;
    int lane = threadIdx.x & 63;
    int node = blockIdx.x * 4 + wid;
    if (node >= NN) return;
    int e0 = row_ptr[node];
    int e1 = row_ptr[node + 1];
    float2 acc = make_float2(0.f, 0.f);
    int e = e0;
    for (; e + 1 < e1; e += 2) {
        int   s0 = esrc[e];
        int   s1 = esrc[e + 1];
        float w0 = ewt[e];
        float w1 = ewt[e + 1];
        float2 v0 = *reinterpret_cast<const float2*>(&Xin[(size_t)s0 * 128 + lane * 2]);
        float2 v1 = *reinterpret_cast<const float2*>(&Xin[(size_t)s1 * 128 + lane * 2]);
        acc.x = fmaf(w0, v0.x, acc.x);
        acc.y = fmaf(w0, v0.y, acc.y);
        acc.x = fmaf(w1, v1.x, acc.x);
        acc.y = fmaf(w1, v1.y, acc.y);
    }
    if (e < e1) {
        int   s0 = esrc[e];
        float w0 = ewt[e];
        float2 v0 = *reinterpret_cast<const float2*>(&Xin[(size_t)s0 * 128 + lane * 2]);
        acc.x = fmaf(w0, v0.x, acc.x);
        acc.y = fmaf(w0, v0.y, acc.y);
    }
    float2 xs = *reinterpret_cast<const float2*>(&Xin[(size_t)node * 128 + lane * 2]);
    acc.x += ALPHA * xs.x;
    acc.y += ALPHA * xs.y;
    if (!FINAL) {
        *reinterpret_cast<float2*>(&out[(size_t)node * 128 + lane * 2]) = acc;
    } else {
        int d = lane * 2;
        float* dst = (d < 64) ? &out[(size_t)node * 64 + d]
                              : &out[(size_t)NN * 64 + (size_t)node * 64 + (d - 64)];
        *reinterpret_cast<float2*>(dst) = acc;
    }
}

// ---------------------------------------------------------------------------
extern "C" void kernel_launch(void* const* d_in, const int* in_sizes, int n_in,
                              void* d_out, int out_size, void* d_ws, size_t ws_size,
                              hipStream_t stream)
{
    const int*   ei       = (const int*)d_in[0];
    const float* ew       = (const float*)d_in[1];
    const float* img_feat = (const float*)d_in[2];
    const float* txt_feat = (const float*)d_in[3];
    const float* img_w    = (const float*)d_in[4];
    const float* img_b    = (const float*)d_in[5];
    const float* txt_w    = (const float*)d_in[6];
    const float* txt_b    = (const float*)d_in[7];
    const float* img_pref = (const float*)d_in[8];
    const float* txt_pref = (const float*)d_in[9];
    float* out = (float*)d_out;

    const size_t XBYTES = (size_t)NN * 128 * 4;
    const size_t PBYTES = (size_t)4 * 40000 * 64 * 4;
    char* ws = (char*)d_ws;
    size_t off = 0;
    auto alloc = [&](size_t bytes) -> void* {
        void* p = ws + off;
        off = (off + bytes + 255) & ~(size_t)255;
        return p;
    };
    float* Xa      = (float*)alloc(XBYTES);
    int*   deg     = (int*)alloc((size_t)NN * 4);
    int*   row_ptr = (int*)alloc((size_t)(NN + 1) * 4);
    int*   cursor  = (int*)alloc((size_t)NN * 4);
    int*   esrc    = (int*)alloc((size_t)N_EDGES * 4);
    float* ewt     = (float*)alloc((size_t)N_EDGES * 4);
    int*   bsums   = (int*)alloc(256 * 4);
    bool haveP = (off + PBYTES) <= ws_size;
    float* P = haveP ? (float*)alloc(PBYTES) : out;   // out is consumed-before-propagate safe
    bool haveXb = (off + XBYTES) <= ws_size;
    float* Xb = haveXb ? (float*)alloc(XBYTES) : out;

    hipMemsetAsync(deg, 0, (size_t)NN * 4, stream);

    copy_pref<<<12500, 256, 0, stream>>>(img_pref, txt_pref, Xa);
    gemm_part<2048, 4><<<dim3(625, 4), 256, 0, stream>>>(img_feat, img_w, P);
    reduce_norm<4, 0><<<10000, 256, 0, stream>>>(P, img_b, Xa);
    gemm_part<384, 3><<<dim3(625, 3), 256, 0, stream>>>(txt_feat, txt_w, P);
    reduce_norm<3, 64><<<10000, 256, 0, stream>>>(P, txt_b, Xa);

    hist_kernel<<<3907, 256, 0, stream>>>(ei, deg);
    scan1<<<137, 256, 0, stream>>>(deg, row_ptr, bsums);
    scan2<<<1, 256, 0, stream>>>(bsums, row_ptr);
    scan3<<<137, 256, 0, stream>>>(row_ptr, cursor, bsums);
    fill_kernel<<<3907, 256, 0, stream>>>(ei, ew, cursor, esrc, ewt);

    propagate<false><<<35000, 256, 0, stream>>>(Xa, row_ptr, esrc, ewt, Xb);
    if (haveXb) {
        propagate<true><<<35000, 256, 0, stream>>>(Xb, row_ptr, esrc, ewt, out);
    } else {
        propagate<true><<<35000, 256, 0, stream>>>(Xb, row_ptr, esrc, ewt, Xa);
        hipMemcpyAsync(out, Xa, XBYTES, hipMemcpyDeviceToDevice, stream);
    }
}

// Round 5
// 470.300 us; speedup vs baseline: 2.2552x; 1.2055x over previous
//
#include <hip/hip_runtime.h>

#define N_USERS 100000
#define N_ITEMS 40000
#define NN      140000          // N_NODES
#define N_EDGES 1000000
#define ALPHA   0.2f

typedef short bf16x8 __attribute__((ext_vector_type(8)));
typedef float f32x4  __attribute__((ext_vector_type(4)));

__device__ __forceinline__ short f2b(float x) {
    unsigned u = __builtin_bit_cast(unsigned, x);
    unsigned r = (u + 0x7FFFu + ((u >> 16) & 1u)) >> 16;
    return (short)r;
}

// ---------------------------------------------------------------------------
// Copy user preference rows into interleaved X[NN][128] (img dims 0..63, txt 64..127)
__global__ void copy_pref(const float* __restrict__ imgp,
                          const float* __restrict__ txtp,
                          float* __restrict__ X)
{
    int tid = blockIdx.x * 256 + threadIdx.x;          // over N_USERS*32 float4s
    if (tid >= N_USERS * 32) return;
    int i  = tid >> 5;
    int c4 = tid & 31;
    float4 v;
    if (c4 < 16) v = *reinterpret_cast<const float4*>(&imgp[(size_t)i * 64 + c4 * 4]);
    else         v = *reinterpret_cast<const float4*>(&txtp[(size_t)i * 64 + (c4 - 16) * 4]);
    *reinterpret_cast<float4*>(&X[(size_t)i * 128 + c4 * 4]) = v;
}

// ---------------------------------------------------------------------------
// W[K][64] f32 -> Wt bf16 in MFMA-B fragment order:
// element (k,n) -> Wt[(k>>5)*2048 + n*32 + ((k>>3)&3)*8 + (k&7)]
template<int K>
__global__ void conv_w(const float* __restrict__ W, short* __restrict__ Wt)
{
    int tid = blockIdx.x * 256 + threadIdx.x;
    if (tid >= K * 64) return;
    int k = tid >> 6, n = tid & 63;
    Wt[(k >> 5) * 2048 + n * 32 + ((k >> 3) & 3) * 8 + (k & 7)] = f2b(W[tid]);
}

// ---------------------------------------------------------------------------
// MFMA GEMM + bias + L2-normalize, LDS-free.
// One wave computes 16 rows x 64 cols. Block = 4 waves = 64 rows. Grid = 625.
// A fragments loaded straight from global f32 (lane l: row l&15, k=(l>>4)*8..+8),
// converted to bf16 in-register. B fragments from pre-swizzled Wt (L2-resident).
template<int K, int COLOFF>
__global__ __launch_bounds__(256, 2)
void gemm_mfma(const float* __restrict__ A, const short* __restrict__ Wt,
               const float* __restrict__ bias, float* __restrict__ X)
{
    constexpr int STEPS = K / 32;
    const int t    = threadIdx.x;
    const int wid  = t >> 6;
    const int lane = t & 63;
    const int lo   = lane & 15;
    const int g    = lane >> 4;
    const int r0w  = blockIdx.x * 64 + wid * 16;

    const float* Ap  = A + (size_t)(r0w + lo) * K + g * 8;
    const short* Bp0 = Wt + lo * 32 + g * 8;

    f32x4 acc[4];
    #pragma unroll
    for (int ct = 0; ct < 4; ++ct) acc[ct] = (f32x4){0.f, 0.f, 0.f, 0.f};

    float4 xA, yA, xB, yB;
    bf16x8 bA[4], bB[4];

    auto loadA = [&](int s, float4& x, float4& y) {
        const float* p = Ap + s * 32;
        x = *reinterpret_cast<const float4*>(p);
        y = *reinterpret_cast<const float4*>(p + 4);
    };
    auto loadB = [&](int s, bf16x8* b) {
        const short* p = Bp0 + s * 2048;
        #pragma unroll
        for (int ct = 0; ct < 4; ++ct) {
            int4 w = *reinterpret_cast<const int4*>(p + ct * 512);
            b[ct] = __builtin_bit_cast(bf16x8, w);
        }
    };
    auto domfma = [&](const float4& x, const float4& y, const bf16x8* b) {
        bf16x8 a;
        a[0] = f2b(x.x); a[1] = f2b(x.y); a[2] = f2b(x.z); a[3] = f2b(x.w);
        a[4] = f2b(y.x); a[5] = f2b(y.y); a[6] = f2b(y.z); a[7] = f2b(y.w);
        #pragma unroll
        for (int ct = 0; ct < 4; ++ct)
            acc[ct] = __builtin_amdgcn_mfma_f32_16x16x32_bf16(a, b[ct], acc[ct], 0, 0, 0);
    };

    loadA(0, xA, yA);
    loadB(0, bA);
    for (int s = 0; s < STEPS; s += 2) {
        loadA(s + 1, xB, yB);          // s+1 < STEPS always (STEPS even)
        loadB(s + 1, bB);
        domfma(xA, yA, bA);
        if (s + 2 < STEPS) {
            loadA(s + 2, xA, yA);
            loadB(s + 2, bA);
        }
        domfma(xB, yB, bB);
    }

    float bia[4];
    #pragma unroll
    for (int ct = 0; ct < 4; ++ct) bia[ct] = bias[ct * 16 + lo];

    #pragma unroll
    for (int r = 0; r < 4; ++r) {
        float v[4];
        float ss = 0.f;
        #pragma unroll
        for (int ct = 0; ct < 4; ++ct) { v[ct] = acc[ct][r] + bia[ct]; ss += v[ct] * v[ct]; }
        ss += __shfl_xor(ss, 1);
        ss += __shfl_xor(ss, 2);
        ss += __shfl_xor(ss, 4);
        ss += __shfl_xor(ss, 8);
        float sc = 1.0f / fmaxf(sqrtf(ss), 1e-12f);
        int grow = r0w + g * 4 + r;
        float* dst = &X[(size_t)(N_USERS + grow) * 128 + COLOFF + lo];
        #pragma unroll
        for (int ct = 0; ct < 4; ++ct) dst[ct * 16] = v[ct] * sc;
    }
}

// ---------------------------------------------------------------------------
// CSR build
__global__ void hist_kernel(const int* __restrict__ ei, int* __restrict__ deg)
{
    int e = blockIdx.x * 256 + threadIdx.x;
    if (e < N_EDGES) atomicAdd(&deg[ei[N_EDGES + e]], 1);
}

__global__ void scan1(const int* __restrict__ deg, int* __restrict__ row_ptr,
                      int* __restrict__ blockSums)
{
    __shared__ int ts[256];
    int t = threadIdx.x, b = blockIdx.x;
    int base = b * 1024 + t * 4;
    int v[4]; int s = 0;
    #pragma unroll
    for (int j = 0; j < 4; j++) {
        v[j] = (base + j < NN) ? deg[base + j] : 0;
        s += v[j];
    }
    ts[t] = s;
    __syncthreads();
    for (int off = 1; off < 256; off <<= 1) {
        int x = (t >= off) ? ts[t - off] : 0;
        __syncthreads();
        ts[t] += x;
        __syncthreads();
    }
    int excl = ts[t] - s;
    int run = excl;
    #pragma unroll
    for (int j = 0; j < 4; j++) {
        if (base + j < NN) row_ptr[base + j] = run;
        run += v[j];
    }
    if (t == 255) blockSums[b] = ts[255];
}

__global__ void scan2(int* __restrict__ blockSums, int* __restrict__ row_ptr)
{
    __shared__ int ts[256];
    int t = threadIdx.x;
    int v = (t < 137) ? blockSums[t] : 0;
    ts[t] = v;
    __syncthreads();
    for (int off = 1; off < 256; off <<= 1) {
        int x = (t >= off) ? ts[t - off] : 0;
        __syncthreads();
        ts[t] += x;
        __syncthreads();
    }
    if (t < 137) blockSums[t] = ts[t] - v;   // exclusive
    if (t == 0) row_ptr[NN] = N_EDGES;
}

__global__ void scan3(int* __restrict__ row_ptr, int* __restrict__ cursor,
                      const int* __restrict__ blockSums)
{
    int t = threadIdx.x, b = blockIdx.x;
    int off = blockSums[b];
    int base = b * 1024 + t * 4;
    #pragma unroll
    for (int j = 0; j < 4; j++) {
        int idx = base + j;
        if (idx < NN) {
            int r = row_ptr[idx] + off;
            row_ptr[idx] = r;
            cursor[idx]  = r;
        }
    }
}

__global__ void fill_kernel(const int* __restrict__ ei, const float* __restrict__ ew,
                            int* __restrict__ cursor, int* __restrict__ esrc,
                            float* __restrict__ ewt)
{
    int e = blockIdx.x * 256 + threadIdx.x;
    if (e >= N_EDGES) return;
    int s = ei[e];
    int d = ei[N_EDGES + e];
    int p = atomicAdd(&cursor[d], 1);
    esrc[p] = s;
    ewt[p]  = ew[e];
}

// ---------------------------------------------------------------------------
// Gather-based propagation: one wave per destination node, lane owns 2 of 128 dims.
// FINAL=true writes split [2][NN][64] layout.
template<bool FINAL>
__global__ __launch_bounds__(256)
void propagate(const float* __restrict__ Xin, const int* __restrict__ row_ptr,
               const int* __restrict__ esrc, const float* __restrict__ ewt,
               float* __restrict__ out)
{
    int wid  = threadIdx.x >> 6;
    int lane = threadIdx.x & 63;
    int node = blockIdx.x * 4 + wid;
    if (node >= NN) return;
    int e0 = row_ptr[node];
    int e1 = row_ptr[node + 1];
    float2 acc = make_float2(0.f, 0.f);
    int e = e0;
    for (; e + 1 < e1; e += 2) {
        int   s0 = esrc[e];
        int   s1 = esrc[e + 1];
        float w0 = ewt[e];
        float w1 = ewt[e + 1];
        float2 v0 = *reinterpret_cast<const float2*>(&Xin[(size_t)s0 * 128 + lane * 2]);
        float2 v1 = *reinterpret_cast<const float2*>(&Xin[(size_t)s1 * 128 + lane * 2]);
        acc.x = fmaf(w0, v0.x, acc.x);
        acc.y = fmaf(w0, v0.y, acc.y);
        acc.x = fmaf(w1, v1.x, acc.x);
        acc.y = fmaf(w1, v1.y, acc.y);
    }
    if (e < e1) {
        int   s0 = esrc[e];
        float w0 = ewt[e];
        float2 v0 = *reinterpret_cast<const float2*>(&Xin[(size_t)s0 * 128 + lane * 2]);
        acc.x = fmaf(w0, v0.x, acc.x);
        acc.y = fmaf(w0, v0.y, acc.y);
    }
    float2 xs = *reinterpret_cast<const float2*>(&Xin[(size_t)node * 128 + lane * 2]);
    acc.x += ALPHA * xs.x;
    acc.y += ALPHA * xs.y;
    if (!FINAL) {
        *reinterpret_cast<float2*>(&out[(size_t)node * 128 + lane * 2]) = acc;
    } else {
        int d = lane * 2;
        float* dst = (d < 64) ? &out[(size_t)node * 64 + d]
                              : &out[(size_t)NN * 64 + (size_t)node * 64 + (d - 64)];
        *reinterpret_cast<float2*>(dst) = acc;
    }
}

// ---------------------------------------------------------------------------
extern "C" void kernel_launch(void* const* d_in, const int* in_sizes, int n_in,
                              void* d_out, int out_size, void* d_ws, size_t ws_size,
                              hipStream_t stream)
{
    const int*   ei       = (const int*)d_in[0];
    const float* ew       = (const float*)d_in[1];
    const float* img_feat = (const float*)d_in[2];
    const float* txt_feat = (const float*)d_in[3];
    const float* img_w    = (const float*)d_in[4];
    const float* img_b    = (const float*)d_in[5];
    const float* txt_w    = (const float*)d_in[6];
    const float* txt_b    = (const float*)d_in[7];
    const float* img_pref = (const float*)d_in[8];
    const float* txt_pref = (const float*)d_in[9];
    float* out = (float*)d_out;

    const size_t XBYTES = (size_t)NN * 128 * 4;
    char* ws = (char*)d_ws;
    size_t off = 0;
    auto alloc = [&](size_t bytes) -> void* {
        void* p = ws + off;
        off = (off + bytes + 255) & ~(size_t)255;
        return p;
    };
    float* Xa      = (float*)alloc(XBYTES);
    int*   deg     = (int*)alloc((size_t)NN * 4);
    int*   row_ptr = (int*)alloc((size_t)(NN + 1) * 4);
    int*   cursor  = (int*)alloc((size_t)NN * 4);
    int*   esrc    = (int*)alloc((size_t)N_EDGES * 4);
    float* ewt     = (float*)alloc((size_t)N_EDGES * 4);
    int*   bsums   = (int*)alloc(256 * 4);
    short* WtImg   = (short*)alloc((size_t)2048 * 64 * 2);
    short* WtTxt   = (short*)alloc((size_t)384 * 64 * 2);
    bool haveXb = (off + XBYTES) <= ws_size;
    float* Xb = haveXb ? (float*)alloc(XBYTES) : out;

    hipMemsetAsync(deg, 0, (size_t)NN * 4, stream);

    conv_w<2048><<<512, 256, 0, stream>>>(img_w, WtImg);
    conv_w< 384><<< 96, 256, 0, stream>>>(txt_w, WtTxt);

    copy_pref<<<12500, 256, 0, stream>>>(img_pref, txt_pref, Xa);
    gemm_mfma<2048, 0 ><<<625, 256, 0, stream>>>(img_feat, WtImg, img_b, Xa);
    gemm_mfma< 384, 64><<<625, 256, 0, stream>>>(txt_feat, WtTxt, txt_b, Xa);

    hist_kernel<<<3907, 256, 0, stream>>>(ei, deg);
    scan1<<<137, 256, 0, stream>>>(deg, row_ptr, bsums);
    scan2<<<1, 256, 0, stream>>>(bsums, row_ptr);
    scan3<<<137, 256, 0, stream>>>(row_ptr, cursor, bsums);
    fill_kernel<<<3907, 256, 0, stream>>>(ei, ew, cursor, esrc, ewt);

    propagate<false><<<35000, 256, 0, stream>>>(Xa, row_ptr, esrc, ewt, Xb);
    if (haveXb) {
        propagate<true><<<35000, 256, 0, stream>>>(Xb, row_ptr, esrc, ewt, out);
    } else {
        propagate<true><<<35000, 256, 0, stream>>>(Xb, row_ptr, esrc, ewt, Xa);
        hipMemcpyAsync(out, Xa, XBYTES, hipMemcpyDeviceToDevice, stream);
    }
}

// Round 6
// 397.286 us; speedup vs baseline: 2.6696x; 1.1838x over previous
//
#include <hip/hip_runtime.h>

#define N_USERS 100000
#define N_ITEMS 40000
#define NN      140000          // N_NODES
#define N_EDGES 1000000
#define ALPHA   0.2f

typedef short bf16x8 __attribute__((ext_vector_type(8)));
typedef float f32x4  __attribute__((ext_vector_type(4)));

__device__ __forceinline__ unsigned short f2b(float x) {
    unsigned u = __builtin_bit_cast(unsigned, x);
    unsigned r = (u + 0x7FFFu + ((u >> 16) & 1u)) >> 16;
    return (unsigned short)r;
}
__device__ __forceinline__ float blo(unsigned u) {       // low bf16 -> f32
    return __builtin_bit_cast(float, u << 16);
}
__device__ __forceinline__ float bhi(unsigned u) {       // high bf16 -> f32
    return __builtin_bit_cast(float, u & 0xFFFF0000u);
}

// ---------------------------------------------------------------------------
// Copy user preference rows into interleaved bf16 X[NN][128] (img 0..63, txt 64..127)
__global__ void copy_pref(const float* __restrict__ imgp,
                          const float* __restrict__ txtp,
                          unsigned short* __restrict__ X)
{
    int tid = blockIdx.x * 256 + threadIdx.x;          // over N_USERS*16 8-dim chunks
    if (tid >= N_USERS * 16) return;
    int i  = tid >> 4;
    int c8 = tid & 15;
    const float* src = (c8 < 8) ? &imgp[(size_t)i * 64 + c8 * 8]
                                : &txtp[(size_t)i * 64 + (c8 - 8) * 8];
    float4 a = *reinterpret_cast<const float4*>(src);
    float4 b = *reinterpret_cast<const float4*>(src + 4);
    unsigned p0 = (unsigned)f2b(a.x) | ((unsigned)f2b(a.y) << 16);
    unsigned p1 = (unsigned)f2b(a.z) | ((unsigned)f2b(a.w) << 16);
    unsigned p2 = (unsigned)f2b(b.x) | ((unsigned)f2b(b.y) << 16);
    unsigned p3 = (unsigned)f2b(b.z) | ((unsigned)f2b(b.w) << 16);
    int4 o = make_int4((int)p0, (int)p1, (int)p2, (int)p3);
    *reinterpret_cast<int4*>(&X[(size_t)i * 128 + c8 * 8]) = o;
}

// ---------------------------------------------------------------------------
// W[K][64] f32 -> Wt bf16 in MFMA-B fragment order:
// element (k,n) -> Wt[(k>>5)*2048 + n*32 + ((k>>3)&3)*8 + (k&7)]
template<int K>
__global__ void conv_w(const float* __restrict__ W, short* __restrict__ Wt)
{
    int tid = blockIdx.x * 256 + threadIdx.x;
    if (tid >= K * 64) return;
    int k = tid >> 6, n = tid & 63;
    Wt[(k >> 5) * 2048 + n * 32 + ((k >> 3) & 3) * 8 + (k & 7)] = (short)f2b(W[tid]);
}

// ---------------------------------------------------------------------------
// MFMA GEMM + bias + L2-normalize, LDS-free; writes bf16 X rows.
template<int K, int COLOFF>
__global__ __launch_bounds__(256, 2)
void gemm_mfma(const float* __restrict__ A, const short* __restrict__ Wt,
               const float* __restrict__ bias, unsigned short* __restrict__ X)
{
    constexpr int STEPS = K / 32;
    const int t    = threadIdx.x;
    const int wid  = t >> 6;
    const int lane = t & 63;
    const int lo   = lane & 15;
    const int g    = lane >> 4;
    const int r0w  = blockIdx.x * 64 + wid * 16;

    const float* Ap  = A + (size_t)(r0w + lo) * K + g * 8;
    const short* Bp0 = Wt + lo * 32 + g * 8;

    f32x4 acc[4];
    #pragma unroll
    for (int ct = 0; ct < 4; ++ct) acc[ct] = (f32x4){0.f, 0.f, 0.f, 0.f};

    float4 xA, yA, xB, yB;
    bf16x8 bA[4], bB[4];

    auto loadA = [&](int s, float4& x, float4& y) {
        const float* p = Ap + s * 32;
        x = *reinterpret_cast<const float4*>(p);
        y = *reinterpret_cast<const float4*>(p + 4);
    };
    auto loadB = [&](int s, bf16x8* b) {
        const short* p = Bp0 + s * 2048;
        #pragma unroll
        for (int ct = 0; ct < 4; ++ct) {
            int4 w = *reinterpret_cast<const int4*>(p + ct * 512);
            b[ct] = __builtin_bit_cast(bf16x8, w);
        }
    };
    auto domfma = [&](const float4& x, const float4& y, const bf16x8* b) {
        bf16x8 a;
        a[0] = (short)f2b(x.x); a[1] = (short)f2b(x.y); a[2] = (short)f2b(x.z); a[3] = (short)f2b(x.w);
        a[4] = (short)f2b(y.x); a[5] = (short)f2b(y.y); a[6] = (short)f2b(y.z); a[7] = (short)f2b(y.w);
        #pragma unroll
        for (int ct = 0; ct < 4; ++ct)
            acc[ct] = __builtin_amdgcn_mfma_f32_16x16x32_bf16(a, b[ct], acc[ct], 0, 0, 0);
    };

    loadA(0, xA, yA);
    loadB(0, bA);
    for (int s = 0; s < STEPS; s += 2) {
        loadA(s + 1, xB, yB);          // STEPS even
        loadB(s + 1, bB);
        domfma(xA, yA, bA);
        if (s + 2 < STEPS) {
            loadA(s + 2, xA, yA);
            loadB(s + 2, bA);
        }
        domfma(xB, yB, bB);
    }

    float bia[4];
    #pragma unroll
    for (int ct = 0; ct < 4; ++ct) bia[ct] = bias[ct * 16 + lo];

    #pragma unroll
    for (int r = 0; r < 4; ++r) {
        float v[4];
        float ss = 0.f;
        #pragma unroll
        for (int ct = 0; ct < 4; ++ct) { v[ct] = acc[ct][r] + bia[ct]; ss += v[ct] * v[ct]; }
        ss += __shfl_xor(ss, 1);
        ss += __shfl_xor(ss, 2);
        ss += __shfl_xor(ss, 4);
        ss += __shfl_xor(ss, 8);
        float sc = 1.0f / fmaxf(sqrtf(ss), 1e-12f);
        int grow = r0w + g * 4 + r;
        unsigned short* dst = &X[(size_t)(N_USERS + grow) * 128 + COLOFF + lo];
        #pragma unroll
        for (int ct = 0; ct < 4; ++ct) dst[ct * 16] = f2b(v[ct] * sc);
    }
}

// ---------------------------------------------------------------------------
// CSR build
__global__ void hist_kernel(const int* __restrict__ ei, int* __restrict__ deg)
{
    int e = blockIdx.x * 256 + threadIdx.x;
    if (e < N_EDGES) atomicAdd(&deg[ei[N_EDGES + e]], 1);
}

__global__ void scan1(const int* __restrict__ deg, int* __restrict__ row_ptr,
                      int* __restrict__ blockSums)
{
    __shared__ int ts[256];
    int t = threadIdx.x, b = blockIdx.x;
    int base = b * 1024 + t * 4;
    int v[4]; int s = 0;
    #pragma unroll
    for (int j = 0; j < 4; j++) {
        v[j] = (base + j < NN) ? deg[base + j] : 0;
        s += v[j];
    }
    ts[t] = s;
    __syncthreads();
    for (int off = 1; off < 256; off <<= 1) {
        int x = (t >= off) ? ts[t - off] : 0;
        __syncthreads();
        ts[t] += x;
        __syncthreads();
    }
    int excl = ts[t] - s;
    int run = excl;
    #pragma unroll
    for (int j = 0; j < 4; j++) {
        if (base + j < NN) row_ptr[base + j] = run;
        run += v[j];
    }
    if (t == 255) blockSums[b] = ts[255];
}

__global__ void scan2(int* __restrict__ blockSums, int* __restrict__ row_ptr)
{
    __shared__ int ts[256];
    int t = threadIdx.x;
    int v = (t < 137) ? blockSums[t] : 0;
    ts[t] = v;
    __syncthreads();
    for (int off = 1; off < 256; off <<= 1) {
        int x = (t >= off) ? ts[t - off] : 0;
        __syncthreads();
        ts[t] += x;
        __syncthreads();
    }
    if (t < 137) blockSums[t] = ts[t] - v;   // exclusive
    if (t == 0) row_ptr[NN] = N_EDGES;
}

__global__ void scan3(int* __restrict__ row_ptr, int* __restrict__ cursor,
                      const int* __restrict__ blockSums)
{
    int t = threadIdx.x, b = blockIdx.x;
    int off = blockSums[b];
    int base = b * 1024 + t * 4;
    #pragma unroll
    for (int j = 0; j < 4; j++) {
        int idx = base + j;
        if (idx < NN) {
            int r = row_ptr[idx] + off;
            row_ptr[idx] = r;
            cursor[idx]  = r;
        }
    }
}

__global__ void fill_kernel(const int* __restrict__ ei, const float* __restrict__ ew,
                            int* __restrict__ cursor, int* __restrict__ esrc,
                            float* __restrict__ ewt)
{
    int e = blockIdx.x * 256 + threadIdx.x;
    if (e >= N_EDGES) return;
    int s = ei[e];
    int d = ei[N_EDGES + e];
    int p = atomicAdd(&cursor[d], 1);
    esrc[p] = s;
    ewt[p]  = ew[e];
}

// ---------------------------------------------------------------------------
// Gather-based propagation over bf16 X. One wave per node; lane owns 2 of 128
// dims (one u32). Edge metadata batch-loaded 64 at a time, broadcast via shfl.
// FINAL=true writes f32 split [2][NN][64] output.
template<bool FINAL>
__global__ __launch_bounds__(256)
void propagate(const unsigned short* __restrict__ Xin, const int* __restrict__ row_ptr,
               const int* __restrict__ esrc, const float* __restrict__ ewt,
               void* __restrict__ outv)
{
    int wid  = threadIdx.x >> 6;
    int lane = threadIdx.x & 63;
    int node = blockIdx.x * 4 + wid;
    if (node >= NN) return;
    int e0 = row_ptr[node];
    int e1 = row_ptr[node + 1];
    float accx = 0.f, accy = 0.f;
    for (int base = e0; base < e1; base += 64) {
        int cnt = e1 - base; if (cnt > 64) cnt = 64;
        int sv = 0; float wv = 0.f;
        if (base + lane < e1) { sv = esrc[base + lane]; wv = ewt[base + lane]; }
        int i = 0;
        for (; i + 1 < cnt; i += 2) {
            int   s0 = __shfl(sv, i);
            int   s1 = __shfl(sv, i + 1);
            float w0 = __shfl(wv, i);
            float w1 = __shfl(wv, i + 1);
            unsigned u0 = *reinterpret_cast<const unsigned*>(&Xin[(size_t)s0 * 128 + lane * 2]);
            unsigned u1 = *reinterpret_cast<const unsigned*>(&Xin[(size_t)s1 * 128 + lane * 2]);
            accx = fmaf(w0, blo(u0), accx);
            accy = fmaf(w0, bhi(u0), accy);
            accx = fmaf(w1, blo(u1), accx);
            accy = fmaf(w1, bhi(u1), accy);
        }
        if (i < cnt) {
            int   s0 = __shfl(sv, i);
            float w0 = __shfl(wv, i);
            unsigned u0 = *reinterpret_cast<const unsigned*>(&Xin[(size_t)s0 * 128 + lane * 2]);
            accx = fmaf(w0, blo(u0), accx);
            accy = fmaf(w0, bhi(u0), accy);
        }
    }
    unsigned us = *reinterpret_cast<const unsigned*>(&Xin[(size_t)node * 128 + lane * 2]);
    accx += ALPHA * blo(us);
    accy += ALPHA * bhi(us);
    if (!FINAL) {
        unsigned short* out = (unsigned short*)outv;
        unsigned p = (unsigned)f2b(accx) | ((unsigned)f2b(accy) << 16);
        *reinterpret_cast<unsigned*>(&out[(size_t)node * 128 + lane * 2]) = p;
    } else {
        float* out = (float*)outv;
        int d = lane * 2;
        float* dst = (d < 64) ? &out[(size_t)node * 64 + d]
                              : &out[(size_t)NN * 64 + (size_t)node * 64 + (d - 64)];
        *reinterpret_cast<float2*>(dst) = make_float2(accx, accy);
    }
}

// ---------------------------------------------------------------------------
extern "C" void kernel_launch(void* const* d_in, const int* in_sizes, int n_in,
                              void* d_out, int out_size, void* d_ws, size_t ws_size,
                              hipStream_t stream)
{
    const int*   ei       = (const int*)d_in[0];
    const float* ew       = (const float*)d_in[1];
    const float* img_feat = (const float*)d_in[2];
    const float* txt_feat = (const float*)d_in[3];
    const float* img_w    = (const float*)d_in[4];
    const float* img_b    = (const float*)d_in[5];
    const float* txt_w    = (const float*)d_in[6];
    const float* txt_b    = (const float*)d_in[7];
    const float* img_pref = (const float*)d_in[8];
    const float* txt_pref = (const float*)d_in[9];
    float* out = (float*)d_out;

    const size_t XBYTES = (size_t)NN * 128 * 2;      // bf16
    char* ws = (char*)d_ws;
    size_t off = 0;
    auto alloc = [&](size_t bytes) -> void* {
        void* p = ws + off;
        off = (off + bytes + 255) & ~(size_t)255;
        return p;
    };
    unsigned short* Xa = (unsigned short*)alloc(XBYTES);
    unsigned short* Xb = (unsigned short*)alloc(XBYTES);
    int*   deg     = (int*)alloc((size_t)NN * 4);
    int*   row_ptr = (int*)alloc((size_t)(NN + 1) * 4);
    int*   cursor  = (int*)alloc((size_t)NN * 4);
    int*   esrc    = (int*)alloc((size_t)N_EDGES * 4);
    float* ewt     = (float*)alloc((size_t)N_EDGES * 4);
    int*   bsums   = (int*)alloc(256 * 4);
    short* WtImg   = (short*)alloc((size_t)2048 * 64 * 2);
    short* WtTxt   = (short*)alloc((size_t)384 * 64 * 2);

    hipMemsetAsync(deg, 0, (size_t)NN * 4, stream);

    conv_w<2048><<<512, 256, 0, stream>>>(img_w, WtImg);
    conv_w< 384><<< 96, 256, 0, stream>>>(txt_w, WtTxt);

    copy_pref<<<6250, 256, 0, stream>>>(img_pref, txt_pref, Xa);
    gemm_mfma<2048, 0 ><<<625, 256, 0, stream>>>(img_feat, WtImg, img_b, Xa);
    gemm_mfma< 384, 64><<<625, 256, 0, stream>>>(txt_feat, WtTxt, txt_b, Xa);

    hist_kernel<<<3907, 256, 0, stream>>>(ei, deg);
    scan1<<<137, 256, 0, stream>>>(deg, row_ptr, bsums);
    scan2<<<1, 256, 0, stream>>>(bsums, row_ptr);
    scan3<<<137, 256, 0, stream>>>(row_ptr, cursor, bsums);
    fill_kernel<<<3907, 256, 0, stream>>>(ei, ew, cursor, esrc, ewt);

    propagate<false><<<35000, 256, 0, stream>>>(Xa, row_ptr, esrc, ewt, Xb);
    propagate<true ><<<35000, 256, 0, stream>>>(Xb, row_ptr, esrc, ewt, out);
}

// Round 7
// 377.797 us; speedup vs baseline: 2.8073x; 1.0516x over previous
//
#include <hip/hip_runtime.h>

#define N_USERS 100000
#define N_ITEMS 40000
#define NN      140000          // N_NODES
#define N_EDGES 1000000
#define ALPHA   0.2f

typedef short bf16x8 __attribute__((ext_vector_type(8)));
typedef float f32x4  __attribute__((ext_vector_type(4)));

__device__ __forceinline__ unsigned short f2b(float x) {
    unsigned u = __builtin_bit_cast(unsigned, x);
    unsigned r = (u + 0x7FFFu + ((u >> 16) & 1u)) >> 16;
    return (unsigned short)r;
}
__device__ __forceinline__ unsigned cvtpk(float lo, float hi) {   // 2xf32 -> packed bf16 (RNE)
    unsigned r;
    asm("v_cvt_pk_bf16_f32 %0, %1, %2" : "=v"(r) : "v"(lo), "v"(hi));
    return r;
}
__device__ __forceinline__ float blo(unsigned u) { return __builtin_bit_cast(float, u << 16); }
__device__ __forceinline__ float bhi(unsigned u) { return __builtin_bit_cast(float, u & 0xFFFF0000u); }

// ---------------------------------------------------------------------------
// prep: block-range fused  [copy_pref | conv_w(img) | conv_w(txt) | hist]
// copy_pref: 6250 blocks; conv img: 512; conv txt: 96; hist: 3907  => 10765
#define PREP_CP   6250
#define PREP_CI   (PREP_CP + 512)
#define PREP_CT   (PREP_CI + 96)
#define PREP_ALL  (PREP_CT + 3907)

__global__ __launch_bounds__(256)
void prep(const float* __restrict__ imgp, const float* __restrict__ txtp,
          unsigned short* __restrict__ X,
          const float* __restrict__ Wi, short* __restrict__ WtImg,
          const float* __restrict__ Wx, short* __restrict__ WtTxt,
          const int* __restrict__ ei, int* __restrict__ deg)
{
    int b = blockIdx.x, t = threadIdx.x;
    if (b < PREP_CP) {
        int tid = b * 256 + t;                   // N_USERS*16 8-dim chunks
        if (tid >= N_USERS * 16) return;
        int i  = tid >> 4;
        int c8 = tid & 15;
        const float* src = (c8 < 8) ? &imgp[(size_t)i * 64 + c8 * 8]
                                    : &txtp[(size_t)i * 64 + (c8 - 8) * 8];
        float4 a = *reinterpret_cast<const float4*>(src);
        float4 c = *reinterpret_cast<const float4*>(src + 4);
        int4 o = make_int4((int)cvtpk(a.x, a.y), (int)cvtpk(a.z, a.w),
                           (int)cvtpk(c.x, c.y), (int)cvtpk(c.z, c.w));
        *reinterpret_cast<int4*>(&X[(size_t)i * 128 + c8 * 8]) = o;
    } else if (b < PREP_CI) {
        int tid = (b - PREP_CP) * 256 + t;       // 2048*64
        int k = tid >> 6, n = tid & 63;
        WtImg[(k >> 5) * 2048 + n * 32 + ((k >> 3) & 3) * 8 + (k & 7)] = (short)f2b(Wi[tid]);
    } else if (b < PREP_CT) {
        int tid = (b - PREP_CI) * 256 + t;       // 384*64
        if (tid >= 384 * 64) return;
        int k = tid >> 6, n = tid & 63;
        WtTxt[(k >> 5) * 2048 + n * 32 + ((k >> 3) & 3) * 8 + (k & 7)] = (short)f2b(Wx[tid]);
    } else {
        int e = (b - PREP_CT) * 256 + t;
        if (e < N_EDGES) atomicAdd(&deg[ei[N_EDGES + e]], 1);
    }
}

// ---------------------------------------------------------------------------
// MFMA GEMM + bias + L2-normalize, LDS-free; writes bf16 X rows.
template<int K, int COLOFF>
__device__ __forceinline__
void gemm_body(int bx, const float* __restrict__ A, const short* __restrict__ Wt,
               const float* __restrict__ bias, unsigned short* __restrict__ X)
{
    constexpr int STEPS = K / 32;
    const int t    = threadIdx.x;
    const int wid  = t >> 6;
    const int lane = t & 63;
    const int lo   = lane & 15;
    const int g    = lane >> 4;
    const int r0w  = bx * 64 + wid * 16;

    const float* Ap  = A + (size_t)(r0w + lo) * K + g * 8;
    const short* Bp0 = Wt + lo * 32 + g * 8;

    f32x4 acc[4];
    #pragma unroll
    for (int ct = 0; ct < 4; ++ct) acc[ct] = (f32x4){0.f, 0.f, 0.f, 0.f};

    float4 xA, yA, xB, yB;
    bf16x8 bA[4], bB[4];

    auto loadA = [&](int s, float4& x, float4& y) {
        const float* p = Ap + s * 32;
        x = *reinterpret_cast<const float4*>(p);
        y = *reinterpret_cast<const float4*>(p + 4);
    };
    auto loadB = [&](int s, bf16x8* bb) {
        const short* p = Bp0 + s * 2048;
        #pragma unroll
        for (int ct = 0; ct < 4; ++ct) {
            int4 w = *reinterpret_cast<const int4*>(p + ct * 512);
            bb[ct] = __builtin_bit_cast(bf16x8, w);
        }
    };
    auto domfma = [&](const float4& x, const float4& y, const bf16x8* bb) {
        int4 ai = make_int4((int)cvtpk(x.x, x.y), (int)cvtpk(x.z, x.w),
                            (int)cvtpk(y.x, y.y), (int)cvtpk(y.z, y.w));
        bf16x8 a = __builtin_bit_cast(bf16x8, ai);
        #pragma unroll
        for (int ct = 0; ct < 4; ++ct)
            acc[ct] = __builtin_amdgcn_mfma_f32_16x16x32_bf16(a, bb[ct], acc[ct], 0, 0, 0);
    };

    loadA(0, xA, yA);
    loadB(0, bA);
    for (int s = 0; s < STEPS; s += 2) {
        loadA(s + 1, xB, yB);          // STEPS even
        loadB(s + 1, bB);
        domfma(xA, yA, bA);
        if (s + 2 < STEPS) {
            loadA(s + 2, xA, yA);
            loadB(s + 2, bA);
        }
        domfma(xB, yB, bB);
    }

    float bia[4];
    #pragma unroll
    for (int ct = 0; ct < 4; ++ct) bia[ct] = bias[ct * 16 + lo];

    #pragma unroll
    for (int r = 0; r < 4; ++r) {
        float v[4];
        float ss = 0.f;
        #pragma unroll
        for (int ct = 0; ct < 4; ++ct) { v[ct] = acc[ct][r] + bia[ct]; ss += v[ct] * v[ct]; }
        ss += __shfl_xor(ss, 1);
        ss += __shfl_xor(ss, 2);
        ss += __shfl_xor(ss, 4);
        ss += __shfl_xor(ss, 8);
        float sc = 1.0f / fmaxf(sqrtf(ss), 1e-12f);
        int grow = r0w + g * 4 + r;
        unsigned short* dst = &X[(size_t)(N_USERS + grow) * 128 + COLOFF + lo];
        #pragma unroll
        for (int ct = 0; ct < 4; ++ct) dst[ct * 16] = f2b(v[ct] * sc);
    }
}

__global__ __launch_bounds__(256, 2)
void gemm_both(const float* __restrict__ Ai, const short* __restrict__ WtImg,
               const float* __restrict__ bi,
               const float* __restrict__ Ax, const short* __restrict__ WtTxt,
               const float* __restrict__ bx, unsigned short* __restrict__ X)
{
    if (blockIdx.x < 625) gemm_body<2048, 0 >(blockIdx.x, Ai, WtImg, bi, X);
    else                  gemm_body< 384, 64>(blockIdx.x - 625, Ax, WtTxt, bx, X);
}

// ---------------------------------------------------------------------------
// CSR build: scans
__global__ void scan1(const int* __restrict__ deg, int* __restrict__ row_ptr,
                      int* __restrict__ blockSums)
{
    __shared__ int ts[256];
    int t = threadIdx.x, b = blockIdx.x;
    int base = b * 1024 + t * 4;
    int v[4]; int s = 0;
    #pragma unroll
    for (int j = 0; j < 4; j++) {
        v[j] = (base + j < NN) ? deg[base + j] : 0;
        s += v[j];
    }
    ts[t] = s;
    __syncthreads();
    for (int off = 1; off < 256; off <<= 1) {
        int x = (t >= off) ? ts[t - off] : 0;
        __syncthreads();
        ts[t] += x;
        __syncthreads();
    }
    int excl = ts[t] - s;
    int run = excl;
    #pragma unroll
    for (int j = 0; j < 4; j++) {
        if (base + j < NN) row_ptr[base + j] = run;
        run += v[j];
    }
    if (t == 255) blockSums[b] = ts[255];
}

__global__ void scan2(int* __restrict__ blockSums, int* __restrict__ row_ptr)
{
    __shared__ int ts[256];
    int t = threadIdx.x;
    int v = (t < 137) ? blockSums[t] : 0;
    ts[t] = v;
    __syncthreads();
    for (int off = 1; off < 256; off <<= 1) {
        int x = (t >= off) ? ts[t - off] : 0;
        __syncthreads();
        ts[t] += x;
        __syncthreads();
    }
    if (t < 137) blockSums[t] = ts[t] - v;   // exclusive
    if (t == 0) row_ptr[NN] = N_EDGES;
}

__global__ void scan3(int* __restrict__ row_ptr, int* __restrict__ cursor,
                      const int* __restrict__ blockSums)
{
    int t = threadIdx.x, b = blockIdx.x;
    int off = blockSums[b];
    int base = b * 1024 + t * 4;
    #pragma unroll
    for (int j = 0; j < 4; j++) {
        int idx = base + j;
        if (idx < NN) {
            int r = row_ptr[idx] + off;
            row_ptr[idx] = r;
            cursor[idx]  = r;
        }
    }
}

__global__ void fill_kernel(const int* __restrict__ ei, const float* __restrict__ ew,
                            int* __restrict__ cursor, int2* __restrict__ epk)
{
    int e = blockIdx.x * 256 + threadIdx.x;
    if (e >= N_EDGES) return;
    int s = ei[e];
    int d = ei[N_EDGES + e];
    int p = atomicAdd(&cursor[d], 1);
    epk[p] = make_int2(s, __builtin_bit_cast(int, ew[e]));
}

// ---------------------------------------------------------------------------
// Gather-based propagation over bf16 X. One wave per node; lane owns 2 of 128
// dims (one u32). Edge (src,w) batch-loaded as int2, broadcast via shfl.
// FINAL=true writes f32 split [2][NN][64] output.
template<bool FINAL>
__global__ __launch_bounds__(256)
void propagate(const unsigned short* __restrict__ Xin, const int* __restrict__ row_ptr,
               const int2* __restrict__ epk, void* __restrict__ outv)
{
    int wid  = threadIdx.x >> 6;
    int lane = threadIdx.x & 63;
    int node = blockIdx.x * 4 + wid;
    if (node >= NN) return;
    int e0 = row_ptr[node];
    int e1 = row_ptr[node + 1];
    float accx = 0.f, accy = 0.f;
    for (int base = e0; base < e1; base += 64) {
        int cnt = e1 - base; if (cnt > 64) cnt = 64;
        int sv = 0, wvb = 0;
        if (base + lane < e1) {
            int2 ev = epk[base + lane];
            sv = ev.x; wvb = ev.y;
        }
        float wv = __builtin_bit_cast(float, wvb);
        int i = 0;
        for (; i + 3 < cnt; i += 4) {
            int   s0 = __shfl(sv, i),     s1 = __shfl(sv, i + 1);
            int   s2 = __shfl(sv, i + 2), s3 = __shfl(sv, i + 3);
            float w0 = __shfl(wv, i),     w1 = __shfl(wv, i + 1);
            float w2 = __shfl(wv, i + 2), w3 = __shfl(wv, i + 3);
            unsigned u0 = *reinterpret_cast<const unsigned*>(&Xin[(size_t)s0 * 128 + lane * 2]);
            unsigned u1 = *reinterpret_cast<const unsigned*>(&Xin[(size_t)s1 * 128 + lane * 2]);
            unsigned u2 = *reinterpret_cast<const unsigned*>(&Xin[(size_t)s2 * 128 + lane * 2]);
            unsigned u3 = *reinterpret_cast<const unsigned*>(&Xin[(size_t)s3 * 128 + lane * 2]);
            accx = fmaf(w0, blo(u0), accx); accy = fmaf(w0, bhi(u0), accy);
            accx = fmaf(w1, blo(u1), accx); accy = fmaf(w1, bhi(u1), accy);
            accx = fmaf(w2, blo(u2), accx); accy = fmaf(w2, bhi(u2), accy);
            accx = fmaf(w3, blo(u3), accx); accy = fmaf(w3, bhi(u3), accy);
        }
        for (; i < cnt; ++i) {
            int   s0 = __shfl(sv, i);
            float w0 = __shfl(wv, i);
            unsigned u0 = *reinterpret_cast<const unsigned*>(&Xin[(size_t)s0 * 128 + lane * 2]);
            accx = fmaf(w0, blo(u0), accx); accy = fmaf(w0, bhi(u0), accy);
        }
    }
    unsigned us = *reinterpret_cast<const unsigned*>(&Xin[(size_t)node * 128 + lane * 2]);
    accx += ALPHA * blo(us);
    accy += ALPHA * bhi(us);
    if (!FINAL) {
        unsigned short* out = (unsigned short*)outv;
        *reinterpret_cast<unsigned*>(&out[(size_t)node * 128 + lane * 2]) = cvtpk(accx, accy);
    } else {
        float* out = (float*)outv;
        int d = lane * 2;
        float* dst = (d < 64) ? &out[(size_t)node * 64 + d]
                              : &out[(size_t)NN * 64 + (size_t)node * 64 + (d - 64)];
        *reinterpret_cast<float2*>(dst) = make_float2(accx, accy);
    }
}

// ---------------------------------------------------------------------------
extern "C" void kernel_launch(void* const* d_in, const int* in_sizes, int n_in,
                              void* d_out, int out_size, void* d_ws, size_t ws_size,
                              hipStream_t stream)
{
    const int*   ei       = (const int*)d_in[0];
    const float* ew       = (const float*)d_in[1];
    const float* img_feat = (const float*)d_in[2];
    const float* txt_feat = (const float*)d_in[3];
    const float* img_w    = (const float*)d_in[4];
    const float* img_b    = (const float*)d_in[5];
    const float* txt_w    = (const float*)d_in[6];
    const float* txt_b    = (const float*)d_in[7];
    const float* img_pref = (const float*)d_in[8];
    const float* txt_pref = (const float*)d_in[9];
    float* out = (float*)d_out;

    const size_t XBYTES = (size_t)NN * 128 * 2;      // bf16
    char* ws = (char*)d_ws;
    size_t off = 0;
    auto alloc = [&](size_t bytes) -> void* {
        void* p = ws + off;
        off = (off + bytes + 255) & ~(size_t)255;
        return p;
    };
    unsigned short* Xa = (unsigned short*)alloc(XBYTES);
    unsigned short* Xb = (unsigned short*)alloc(XBYTES);
    int*   deg     = (int*)alloc((size_t)NN * 4);
    int*   row_ptr = (int*)alloc((size_t)(NN + 1) * 4);
    int*   cursor  = (int*)alloc((size_t)NN * 4);
    int2*  epk     = (int2*)alloc((size_t)N_EDGES * 8);
    int*   bsums   = (int*)alloc(256 * 4);
    short* WtImg   = (short*)alloc((size_t)2048 * 64 * 2);
    short* WtTxt   = (short*)alloc((size_t)384 * 64 * 2);

    hipMemsetAsync(deg, 0, (size_t)NN * 4, stream);

    prep<<<PREP_ALL, 256, 0, stream>>>(img_pref, txt_pref, Xa,
                                       img_w, WtImg, txt_w, WtTxt, ei, deg);

    gemm_both<<<1250, 256, 0, stream>>>(img_feat, WtImg, img_b,
                                        txt_feat, WtTxt, txt_b, Xa);

    scan1<<<137, 256, 0, stream>>>(deg, row_ptr, bsums);
    scan2<<<1, 256, 0, stream>>>(bsums, row_ptr);
    scan3<<<137, 256, 0, stream>>>(row_ptr, cursor, bsums);
    fill_kernel<<<3907, 256, 0, stream>>>(ei, ew, cursor, epk);

    propagate<false><<<35000, 256, 0, stream>>>(Xa, row_ptr, epk, Xb);
    propagate<true ><<<35000, 256, 0, stream>>>(Xb, row_ptr, epk, out);
}

// Round 10
// 342.502 us; speedup vs baseline: 3.0966x; 1.1031x over previous
//
#include <hip/hip_runtime.h>

#define N_USERS 100000
#define N_ITEMS 40000
#define NN      140000          // N_NODES
#define N_EDGES 1000000
#define ALPHA   0.2f

typedef short bf16x8 __attribute__((ext_vector_type(8)));
typedef float f32x4  __attribute__((ext_vector_type(4)));

__device__ __forceinline__ unsigned short f2b(float x) {
    unsigned u = __builtin_bit_cast(unsigned, x);
    unsigned r = (u + 0x7FFFu + ((u >> 16) & 1u)) >> 16;
    return (unsigned short)r;
}
__device__ __forceinline__ unsigned cvtpk(float lo, float hi) {   // 2xf32 -> packed bf16 (RNE)
    unsigned r;
    asm("v_cvt_pk_bf16_f32 %0, %1, %2" : "=v"(r) : "v"(lo), "v"(hi));
    return r;
}
__device__ __forceinline__ float blo(unsigned u) { return __builtin_bit_cast(float, u << 16); }
__device__ __forceinline__ float bhi(unsigned u) { return __builtin_bit_cast(float, u & 0xFFFF0000u); }

// ---------------------------------------------------------------------------
// prep: block-range fused  [copy_pref | conv_w(img) | conv_w(txt) | hist]
#define PREP_CP   6250
#define PREP_CI   (PREP_CP + 512)
#define PREP_CT   (PREP_CI + 96)
#define PREP_ALL  (PREP_CT + 3907)

__global__ __launch_bounds__(256)
void prep(const float* __restrict__ imgp, const float* __restrict__ txtp,
          unsigned short* __restrict__ X,
          const float* __restrict__ Wi, short* __restrict__ WtImg,
          const float* __restrict__ Wx, short* __restrict__ WtTxt,
          const int* __restrict__ ei, int* __restrict__ deg)
{
    int b = blockIdx.x, t = threadIdx.x;
    if (b < PREP_CP) {
        int tid = b * 256 + t;                   // N_USERS*16 8-dim chunks
        if (tid >= N_USERS * 16) return;
        int i  = tid >> 4;
        int c8 = tid & 15;
        const float* src = (c8 < 8) ? &imgp[(size_t)i * 64 + c8 * 8]
                                    : &txtp[(size_t)i * 64 + (c8 - 8) * 8];
        float4 a = *reinterpret_cast<const float4*>(src);
        float4 c = *reinterpret_cast<const float4*>(src + 4);
        int4 o = make_int4((int)cvtpk(a.x, a.y), (int)cvtpk(a.z, a.w),
                           (int)cvtpk(c.x, c.y), (int)cvtpk(c.z, c.w));
        *reinterpret_cast<int4*>(&X[(size_t)i * 128 + c8 * 8]) = o;
    } else if (b < PREP_CI) {
        int tid = (b - PREP_CP) * 256 + t;       // 2048*64
        int k = tid >> 6, n = tid & 63;
        WtImg[(k >> 5) * 2048 + n * 32 + ((k >> 3) & 3) * 8 + (k & 7)] = (short)f2b(Wi[tid]);
    } else if (b < PREP_CT) {
        int tid = (b - PREP_CI) * 256 + t;       // 384*64
        if (tid >= 384 * 64) return;
        int k = tid >> 6, n = tid & 63;
        WtTxt[(k >> 5) * 2048 + n * 32 + ((k >> 3) & 3) * 8 + (k & 7)] = (short)f2b(Wx[tid]);
    } else {
        int e = (b - PREP_CT) * 256 + t;
        if (e < N_EDGES) atomicAdd(&deg[ei[N_EDGES + e]], 1);
    }
}

// ---------------------------------------------------------------------------
// MFMA GEMM + bias + L2-normalize, LDS-free; R6-proven 2-deep ping-pong.
template<int K, int COLOFF>
__device__ __forceinline__
void gemm_body(int bx, const float* __restrict__ A, const short* __restrict__ Wt,
               const float* __restrict__ bias, unsigned short* __restrict__ X)
{
    constexpr int STEPS = K / 32;     // 64 (img) / 12 (txt), both even
    const int t    = threadIdx.x;
    const int wid  = t >> 6;
    const int lane = t & 63;
    const int lo   = lane & 15;
    const int g    = lane >> 4;
    const int r0w  = bx * 64 + wid * 16;

    const float* Ap  = A + (size_t)(r0w + lo) * K + g * 8;
    const short* Bp0 = Wt + lo * 32 + g * 8;

    f32x4 acc[4];
    #pragma unroll
    for (int ct = 0; ct < 4; ++ct) acc[ct] = (f32x4){0.f, 0.f, 0.f, 0.f};

    float4 xA, yA, xB, yB;
    bf16x8 bA[4], bB[4];

    auto loadA = [&](int s, float4& x, float4& y) {
        const float* p = Ap + s * 32;
        x = *reinterpret_cast<const float4*>(p);
        y = *reinterpret_cast<const float4*>(p + 4);
    };
    auto loadB = [&](int s, bf16x8* bb) {
        const short* p = Bp0 + s * 2048;
        #pragma unroll
        for (int ct = 0; ct < 4; ++ct) {
            int4 w = *reinterpret_cast<const int4*>(p + ct * 512);
            bb[ct] = __builtin_bit_cast(bf16x8, w);
        }
    };
    auto domfma = [&](const float4& x, const float4& y, const bf16x8* bb) {
        int4 ai = make_int4((int)cvtpk(x.x, x.y), (int)cvtpk(x.z, x.w),
                            (int)cvtpk(y.x, y.y), (int)cvtpk(y.z, y.w));
        bf16x8 a = __builtin_bit_cast(bf16x8, ai);
        #pragma unroll
        for (int ct = 0; ct < 4; ++ct)
            acc[ct] = __builtin_amdgcn_mfma_f32_16x16x32_bf16(a, bb[ct], acc[ct], 0, 0, 0);
    };

    loadA(0, xA, yA);
    loadB(0, bA);
    for (int s = 0; s < STEPS; s += 2) {
        loadA(s + 1, xB, yB);          // STEPS even
        loadB(s + 1, bB);
        domfma(xA, yA, bA);
        if (s + 2 < STEPS) {
            loadA(s + 2, xA, yA);
            loadB(s + 2, bA);
        }
        domfma(xB, yB, bB);
    }

    float bia[4];
    #pragma unroll
    for (int ct = 0; ct < 4; ++ct) bia[ct] = bias[ct * 16 + lo];

    #pragma unroll
    for (int r = 0; r < 4; ++r) {
        float v[4];
        float ss = 0.f;
        #pragma unroll
        for (int ct = 0; ct < 4; ++ct) { v[ct] = acc[ct][r] + bia[ct]; ss += v[ct] * v[ct]; }
        ss += __shfl_xor(ss, 1);
        ss += __shfl_xor(ss, 2);
        ss += __shfl_xor(ss, 4);
        ss += __shfl_xor(ss, 8);
        float sc = 1.0f / fmaxf(sqrtf(ss), 1e-12f);
        int grow = r0w + g * 4 + r;
        unsigned short* dst = &X[(size_t)(N_USERS + grow) * 128 + COLOFF + lo];
        #pragma unroll
        for (int ct = 0; ct < 4; ++ct) dst[ct * 16] = f2b(v[ct] * sc);
    }
}

// Fused: blocks 0..624 img GEMM, 625..1249 txt GEMM, 1250.. fill (CSR scatter)
__global__ __launch_bounds__(256, 2)
void gemm_fill(const float* __restrict__ Ai, const short* __restrict__ WtImg,
               const float* __restrict__ bi,
               const float* __restrict__ Ax, const short* __restrict__ WtTxt,
               const float* __restrict__ bx, unsigned short* __restrict__ X,
               const int* __restrict__ ei, const float* __restrict__ ew,
               int* __restrict__ cursor, int2* __restrict__ epk)
{
    int b = blockIdx.x;
    if (b < 625)       gemm_body<2048, 0 >(b, Ai, WtImg, bi, X);
    else if (b < 1250) gemm_body< 384, 64>(b - 625, Ax, WtTxt, bx, X);
    else {
        int e = (b - 1250) * 256 + threadIdx.x;
        if (e >= N_EDGES) return;
        int s = ei[e];
        int d = ei[N_EDGES + e];
        int p = atomicAdd(&cursor[d], 1);
        epk[p] = make_int2(s, __builtin_bit_cast(int, ew[e]));
    }
}

// ---------------------------------------------------------------------------
// CSR scans
__global__ void scan1(const int* __restrict__ deg, int* __restrict__ row_ptr,
                      int* __restrict__ blockSums)
{
    __shared__ int ts[256];
    int t = threadIdx.x, b = blockIdx.x;
    int base = b * 1024 + t * 4;
    int v[4]; int s = 0;
    #pragma unroll
    for (int j = 0; j < 4; j++) {
        v[j] = (base + j < NN) ? deg[base + j] : 0;
        s += v[j];
    }
    ts[t] = s;
    __syncthreads();
    for (int off = 1; off < 256; off <<= 1) {
        int x = (t >= off) ? ts[t - off] : 0;
        __syncthreads();
        ts[t] += x;
        __syncthreads();
    }
    int excl = ts[t] - s;
    int run = excl;
    #pragma unroll
    for (int j = 0; j < 4; j++) {
        if (base + j < NN) row_ptr[base + j] = run;
        run += v[j];
    }
    if (t == 255) blockSums[b] = ts[255];
}

// merged scan2+scan3: each block re-reduces blockSums[0..b-1] (137 entries, cheap)
__global__ void scan23(const int* __restrict__ blockSums, int* __restrict__ row_ptr,
                       int* __restrict__ cursor)
{
    __shared__ int ts[256];
    int t = threadIdx.x, b = blockIdx.x;
    ts[t] = (t < b) ? blockSums[t] : 0;     // b <= 136 < 256
    __syncthreads();
    for (int off = 128; off > 0; off >>= 1) {
        if (t < off) ts[t] += ts[t + off];
        __syncthreads();
    }
    int off0 = ts[0];
    int base = b * 1024 + t * 4;
    #pragma unroll
    for (int j = 0; j < 4; j++) {
        int idx = base + j;
        if (idx < NN) {
            int r = row_ptr[idx] + off0;
            row_ptr[idx] = r;
            cursor[idx]  = r;
        }
    }
    if (b == 0 && t == 0) row_ptr[NN] = N_EDGES;
}

// ---------------------------------------------------------------------------
// Propagation (R6-proven structure): one wave per node, lane owns 2 of 128 dims
// (one u32). Edge (src,w) batch-loaded 64/wave as int2, broadcast via shfl.
// FINAL=true writes f32 split [2][NN][64] output.
template<bool FINAL>
__global__ __launch_bounds__(256)
void propagate(const unsigned short* __restrict__ Xin, const int* __restrict__ row_ptr,
               const int2* __restrict__ epk, void* __restrict__ outv)
{
    int wid  = threadIdx.x >> 6;
    int lane = threadIdx.x & 63;
    int node = blockIdx.x * 4 + wid;
    if (node >= NN) return;
    int e0 = row_ptr[node];
    int e1 = row_ptr[node + 1];
    float accx = 0.f, accy = 0.f;
    for (int base = e0; base < e1; base += 64) {
        int cnt = e1 - base; if (cnt > 64) cnt = 64;
        int sv = 0, wvb = 0;
        if (base + lane < e1) {
            int2 ev = epk[base + lane];
            sv = ev.x; wvb = ev.y;
        }
        float wv = __builtin_bit_cast(float, wvb);
        int i = 0;
        for (; i + 3 < cnt; i += 4) {
            int   s0 = __shfl(sv, i),     s1 = __shfl(sv, i + 1);
            int   s2 = __shfl(sv, i + 2), s3 = __shfl(sv, i + 3);
            float w0 = __shfl(wv, i),     w1 = __shfl(wv, i + 1);
            float w2 = __shfl(wv, i + 2), w3 = __shfl(wv, i + 3);
            unsigned u0 = *reinterpret_cast<const unsigned*>(&Xin[(size_t)s0 * 128 + lane * 2]);
            unsigned u1 = *reinterpret_cast<const unsigned*>(&Xin[(size_t)s1 * 128 + lane * 2]);
            unsigned u2 = *reinterpret_cast<const unsigned*>(&Xin[(size_t)s2 * 128 + lane * 2]);
            unsigned u3 = *reinterpret_cast<const unsigned*>(&Xin[(size_t)s3 * 128 + lane * 2]);
            accx = fmaf(w0, blo(u0), accx); accy = fmaf(w0, bhi(u0), accy);
            accx = fmaf(w1, blo(u1), accx); accy = fmaf(w1, bhi(u1), accy);
            accx = fmaf(w2, blo(u2), accx); accy = fmaf(w2, bhi(u2), accy);
            accx = fmaf(w3, blo(u3), accx); accy = fmaf(w3, bhi(u3), accy);
        }
        for (; i < cnt; ++i) {
            int   s0 = __shfl(sv, i);
            float w0 = __shfl(wv, i);
            unsigned u0 = *reinterpret_cast<const unsigned*>(&Xin[(size_t)s0 * 128 + lane * 2]);
            accx = fmaf(w0, blo(u0), accx); accy = fmaf(w0, bhi(u0), accy);
        }
    }
    unsigned us = *reinterpret_cast<const unsigned*>(&Xin[(size_t)node * 128 + lane * 2]);
    accx += ALPHA * blo(us);
    accy += ALPHA * bhi(us);
    if (!FINAL) {
        unsigned short* out = (unsigned short*)outv;
        *reinterpret_cast<unsigned*>(&out[(size_t)node * 128 + lane * 2]) = cvtpk(accx, accy);
    } else {
        float* out = (float*)outv;
        int d = lane * 2;
        float* dst = (d < 64) ? &out[(size_t)node * 64 + d]
                              : &out[(size_t)NN * 64 + (size_t)node * 64 + (d - 64)];
        *reinterpret_cast<float2*>(dst) = make_float2(accx, accy);
    }
}

// ---------------------------------------------------------------------------
extern "C" void kernel_launch(void* const* d_in, const int* in_sizes, int n_in,
                              void* d_out, int out_size, void* d_ws, size_t ws_size,
                              hipStream_t stream)
{
    const int*   ei       = (const int*)d_in[0];
    const float* ew       = (const float*)d_in[1];
    const float* img_feat = (const float*)d_in[2];
    const float* txt_feat = (const float*)d_in[3];
    const float* img_w    = (const float*)d_in[4];
    const float* img_b    = (const float*)d_in[5];
    const float* txt_w    = (const float*)d_in[6];
    const float* txt_b    = (const float*)d_in[7];
    const float* img_pref = (const float*)d_in[8];
    const float* txt_pref = (const float*)d_in[9];
    float* out = (float*)d_out;

    const size_t XBYTES = (size_t)NN * 128 * 2;      // bf16
    char* ws = (char*)d_ws;
    size_t off = 0;
    auto alloc = [&](size_t bytes) -> void* {
        void* p = ws + off;
        off = (off + bytes + 255) & ~(size_t)255;
        return p;
    };
    unsigned short* Xa = (unsigned short*)alloc(XBYTES);
    unsigned short* Xb = (unsigned short*)alloc(XBYTES);
    int*   deg     = (int*)alloc((size_t)NN * 4);
    int*   row_ptr = (int*)alloc((size_t)(NN + 1) * 4);
    int*   cursor  = (int*)alloc((size_t)NN * 4);
    int2*  epk     = (int2*)alloc((size_t)N_EDGES * 8);
    int*   bsums   = (int*)alloc(256 * 4);
    short* WtImg   = (short*)alloc((size_t)2048 * 64 * 2);
    short* WtTxt   = (short*)alloc((size_t)384 * 64 * 2);

    hipMemsetAsync(deg, 0, (size_t)NN * 4, stream);

    prep<<<PREP_ALL, 256, 0, stream>>>(img_pref, txt_pref, Xa,
                                       img_w, WtImg, txt_w, WtTxt, ei, deg);

    scan1<<<137, 256, 0, stream>>>(deg, row_ptr, bsums);
    scan23<<<137, 256, 0, stream>>>(bsums, row_ptr, cursor);

    gemm_fill<<<1250 + 3907, 256, 0, stream>>>(img_feat, WtImg, img_b,
                                               txt_feat, WtTxt, txt_b, Xa,
                                               ei, ew, cursor, epk);

    propagate<false><<<35000, 256, 0, stream>>>(Xa, row_ptr, epk, Xb);
    propagate<true ><<<35000, 256, 0, stream>>>(Xb, row_ptr, epk, out);
}

// Round 11
// 334.460 us; speedup vs baseline: 3.1711x; 1.0240x over previous
//
#include <hip/hip_runtime.h>

#define N_USERS 100000
#define N_ITEMS 40000
#define NN      140000          // N_NODES
#define N_EDGES 1000000
#define ALPHA   0.2f

typedef short bf16x8 __attribute__((ext_vector_type(8)));
typedef float f32x4  __attribute__((ext_vector_type(4)));

__device__ __forceinline__ unsigned short f2b(float x) {
    unsigned u = __builtin_bit_cast(unsigned, x);
    unsigned r = (u + 0x7FFFu + ((u >> 16) & 1u)) >> 16;
    return (unsigned short)r;
}
__device__ __forceinline__ unsigned cvtpk(float lo, float hi) {   // 2xf32 -> packed bf16 (RNE)
    unsigned r;
    asm("v_cvt_pk_bf16_f32 %0, %1, %2" : "=v"(r) : "v"(lo), "v"(hi));
    return r;
}
__device__ __forceinline__ float blo(unsigned u) { return __builtin_bit_cast(float, u << 16); }
__device__ __forceinline__ float bhi(unsigned u) { return __builtin_bit_cast(float, u & 0xFFFF0000u); }

// ---------------------------------------------------------------------------
// prep: block-range fused  [copy_pref | conv_w(img) | conv_w(txt) | hist]
#define PREP_CP   6250
#define PREP_CI   (PREP_CP + 512)
#define PREP_CT   (PREP_CI + 96)
#define PREP_ALL  (PREP_CT + 3907)

__global__ __launch_bounds__(256)
void prep(const float* __restrict__ imgp, const float* __restrict__ txtp,
          unsigned short* __restrict__ X,
          const float* __restrict__ Wi, short* __restrict__ WtImg,
          const float* __restrict__ Wx, short* __restrict__ WtTxt,
          const int* __restrict__ ei, int* __restrict__ deg)
{
    int b = blockIdx.x, t = threadIdx.x;
    if (b < PREP_CP) {
        int tid = b * 256 + t;                   // N_USERS*16 8-dim chunks
        if (tid >= N_USERS * 16) return;
        int i  = tid >> 4;
        int c8 = tid & 15;
        const float* src = (c8 < 8) ? &imgp[(size_t)i * 64 + c8 * 8]
                                    : &txtp[(size_t)i * 64 + (c8 - 8) * 8];
        float4 a = *reinterpret_cast<const float4*>(src);
        float4 c = *reinterpret_cast<const float4*>(src + 4);
        int4 o = make_int4((int)cvtpk(a.x, a.y), (int)cvtpk(a.z, a.w),
                           (int)cvtpk(c.x, c.y), (int)cvtpk(c.z, c.w));
        *reinterpret_cast<int4*>(&X[(size_t)i * 128 + c8 * 8]) = o;
    } else if (b < PREP_CI) {
        int tid = (b - PREP_CP) * 256 + t;       // 2048*64
        int k = tid >> 6, n = tid & 63;
        WtImg[(k >> 5) * 2048 + n * 32 + ((k >> 3) & 3) * 8 + (k & 7)] = (short)f2b(Wi[tid]);
    } else if (b < PREP_CT) {
        int tid = (b - PREP_CI) * 256 + t;       // 384*64
        if (tid >= 384 * 64) return;
        int k = tid >> 6, n = tid & 63;
        WtTxt[(k >> 5) * 2048 + n * 32 + ((k >> 3) & 3) * 8 + (k & 7)] = (short)f2b(Wx[tid]);
    } else {
        int e = (b - PREP_CT) * 256 + t;
        if (e < N_EDGES) atomicAdd(&deg[ei[N_EDGES + e]], 1);
    }
}

// ---------------------------------------------------------------------------
// MFMA GEMM + bias + L2-normalize, LDS-free.
// 2 waves/block; each wave owns 32 rows as TWO 16-row row-blocks (rb0/rb1)
// sharing the B fragments. 2-deep ping-pong (R6-proven schedule, duplicated).
template<int K, int COLOFF>
__device__ __forceinline__
void gemm_body(int bx, const float* __restrict__ A, const short* __restrict__ Wt,
               const float* __restrict__ bias, unsigned short* __restrict__ X)
{
    constexpr int STEPS = K / 32;     // 64 (img) / 12 (txt), both even
    const int t    = threadIdx.x;     // 0..127
    const int wid  = t >> 6;          // 0..1
    const int lane = t & 63;
    const int lo   = lane & 15;
    const int g    = lane >> 4;
    const int r0   = bx * 64 + wid * 32;   // wave's 32 rows; rb0: +0..15, rb1: +16..31

    const float* Ap0 = A + (size_t)(r0 + lo) * K + g * 8;
    const float* Ap1 = A + (size_t)(r0 + 16 + lo) * K + g * 8;
    const short* Bp0 = Wt + lo * 32 + g * 8;

    f32x4 acc0[4], acc1[4];
    #pragma unroll
    for (int ct = 0; ct < 4; ++ct) {
        acc0[ct] = (f32x4){0.f, 0.f, 0.f, 0.f};
        acc1[ct] = (f32x4){0.f, 0.f, 0.f, 0.f};
    }

    float4 x0A, y0A, x0B, y0B, x1A, y1A, x1B, y1B;
    bf16x8 bA[4], bB[4];

    auto loadA = [&](const float* Ap, int s, float4& x, float4& y) {
        const float* p = Ap + s * 32;
        x = *reinterpret_cast<const float4*>(p);
        y = *reinterpret_cast<const float4*>(p + 4);
    };
    auto loadB = [&](int s, bf16x8* bb) {
        const short* p = Bp0 + s * 2048;
        #pragma unroll
        for (int ct = 0; ct < 4; ++ct) {
            int4 w = *reinterpret_cast<const int4*>(p + ct * 512);
            bb[ct] = __builtin_bit_cast(bf16x8, w);
        }
    };
    auto domfma = [&](f32x4* acc, const float4& x, const float4& y, const bf16x8* bb) {
        int4 ai = make_int4((int)cvtpk(x.x, x.y), (int)cvtpk(x.z, x.w),
                            (int)cvtpk(y.x, y.y), (int)cvtpk(y.z, y.w));
        bf16x8 a = __builtin_bit_cast(bf16x8, ai);
        #pragma unroll
        for (int ct = 0; ct < 4; ++ct)
            acc[ct] = __builtin_amdgcn_mfma_f32_16x16x32_bf16(a, bb[ct], acc[ct], 0, 0, 0);
    };

    loadA(Ap0, 0, x0A, y0A);
    loadA(Ap1, 0, x1A, y1A);
    loadB(0, bA);
    for (int s = 0; s < STEPS; s += 2) {
        loadA(Ap0, s + 1, x0B, y0B);          // STEPS even -> s+1 always valid
        loadA(Ap1, s + 1, x1B, y1B);
        loadB(s + 1, bB);
        domfma(acc0, x0A, y0A, bA);
        domfma(acc1, x1A, y1A, bA);
        if (s + 2 < STEPS) {
            loadA(Ap0, s + 2, x0A, y0A);
            loadA(Ap1, s + 2, x1A, y1A);
            loadB(s + 2, bA);
        }
        domfma(acc0, x0B, y0B, bB);
        domfma(acc1, x1B, y1B, bB);
    }

    float bia[4];
    #pragma unroll
    for (int ct = 0; ct < 4; ++ct) bia[ct] = bias[ct * 16 + lo];

    #pragma unroll
    for (int rb = 0; rb < 2; ++rb) {
        f32x4* acc = rb ? acc1 : acc0;
        int rbase = r0 + rb * 16;
        #pragma unroll
        for (int r = 0; r < 4; ++r) {
            float v[4];
            float ss = 0.f;
            #pragma unroll
            for (int ct = 0; ct < 4; ++ct) { v[ct] = acc[ct][r] + bia[ct]; ss += v[ct] * v[ct]; }
            ss += __shfl_xor(ss, 1);
            ss += __shfl_xor(ss, 2);
            ss += __shfl_xor(ss, 4);
            ss += __shfl_xor(ss, 8);
            float sc = 1.0f / fmaxf(sqrtf(ss), 1e-12f);
            int grow = rbase + g * 4 + r;
            unsigned short* dst = &X[(size_t)(N_USERS + grow) * 128 + COLOFF + lo];
            #pragma unroll
            for (int ct = 0; ct < 4; ++ct) dst[ct * 16] = f2b(v[ct] * sc);
        }
    }
}

// Fused (128-thread blocks): 0..624 img GEMM, 625..1249 txt GEMM, 1250.. fill
__global__ __launch_bounds__(128, 1)
void gemm_fill(const float* __restrict__ Ai, const short* __restrict__ WtImg,
               const float* __restrict__ bi,
               const float* __restrict__ Ax, const short* __restrict__ WtTxt,
               const float* __restrict__ bx, unsigned short* __restrict__ X,
               const int* __restrict__ ei, const float* __restrict__ ew,
               int* __restrict__ cursor, int2* __restrict__ epk)
{
    int b = blockIdx.x;
    if (b < 625)       gemm_body<2048, 0 >(b, Ai, WtImg, bi, X);
    else if (b < 1250) gemm_body< 384, 64>(b - 625, Ax, WtTxt, bx, X);
    else {
        int e = (b - 1250) * 128 + threadIdx.x;
        if (e >= N_EDGES) return;
        int s = ei[e];
        int d = ei[N_EDGES + e];
        int p = atomicAdd(&cursor[d], 1);
        epk[p] = make_int2(s, __builtin_bit_cast(int, ew[e]));
    }
}

// ---------------------------------------------------------------------------
// CSR scans
__global__ void scan1(const int* __restrict__ deg, int* __restrict__ row_ptr,
                      int* __restrict__ blockSums)
{
    __shared__ int ts[256];
    int t = threadIdx.x, b = blockIdx.x;
    int base = b * 1024 + t * 4;
    int v[4]; int s = 0;
    #pragma unroll
    for (int j = 0; j < 4; j++) {
        v[j] = (base + j < NN) ? deg[base + j] : 0;
        s += v[j];
    }
    ts[t] = s;
    __syncthreads();
    for (int off = 1; off < 256; off <<= 1) {
        int x = (t >= off) ? ts[t - off] : 0;
        __syncthreads();
        ts[t] += x;
        __syncthreads();
    }
    int excl = ts[t] - s;
    int run = excl;
    #pragma unroll
    for (int j = 0; j < 4; j++) {
        if (base + j < NN) row_ptr[base + j] = run;
        run += v[j];
    }
    if (t == 255) blockSums[b] = ts[255];
}

// merged scan2+scan3: each block re-reduces blockSums[0..b-1] (137 entries, cheap)
__global__ void scan23(const int* __restrict__ blockSums, int* __restrict__ row_ptr,
                       int* __restrict__ cursor)
{
    __shared__ int ts[256];
    int t = threadIdx.x, b = blockIdx.x;
    ts[t] = (t < b) ? blockSums[t] : 0;     // b <= 136 < 256
    __syncthreads();
    for (int off = 128; off > 0; off >>= 1) {
        if (t < off) ts[t] += ts[t + off];
        __syncthreads();
    }
    int off0 = ts[0];
    int base = b * 1024 + t * 4;
    #pragma unroll
    for (int j = 0; j < 4; j++) {
        int idx = base + j;
        if (idx < NN) {
            int r = row_ptr[idx] + off0;
            row_ptr[idx] = r;
            cursor[idx]  = r;
        }
    }
    if (b == 0 && t == 0) row_ptr[NN] = N_EDGES;
}

// ---------------------------------------------------------------------------
// Propagation (R6-proven structure): one wave per node, lane owns 2 of 128 dims
// (one u32). Edge (src,w) batch-loaded 64/wave as int2, broadcast via shfl.
// FINAL=true writes f32 split [2][NN][64] output.
template<bool FINAL>
__global__ __launch_bounds__(256)
void propagate(const unsigned short* __restrict__ Xin, const int* __restrict__ row_ptr,
               const int2* __restrict__ epk, void* __restrict__ outv)
{
    int wid  = threadIdx.x >> 6;
    int lane = threadIdx.x & 63;
    int node = blockIdx.x * 4 + wid;
    if (node >= NN) return;
    int e0 = row_ptr[node];
    int e1 = row_ptr[node + 1];
    float accx = 0.f, accy = 0.f;
    for (int base = e0; base < e1; base += 64) {
        int cnt = e1 - base; if (cnt > 64) cnt = 64;
        int sv = 0, wvb = 0;
        if (base + lane < e1) {
            int2 ev = epk[base + lane];
            sv = ev.x; wvb = ev.y;
        }
        float wv = __builtin_bit_cast(float, wvb);
        int i = 0;
        for (; i + 3 < cnt; i += 4) {
            int   s0 = __shfl(sv, i),     s1 = __shfl(sv, i + 1);
            int   s2 = __shfl(sv, i + 2), s3 = __shfl(sv, i + 3);
            float w0 = __shfl(wv, i),     w1 = __shfl(wv, i + 1);
            float w2 = __shfl(wv, i + 2), w3 = __shfl(wv, i + 3);
            unsigned u0 = *reinterpret_cast<const unsigned*>(&Xin[(size_t)s0 * 128 + lane * 2]);
            unsigned u1 = *reinterpret_cast<const unsigned*>(&Xin[(size_t)s1 * 128 + lane * 2]);
            unsigned u2 = *reinterpret_cast<const unsigned*>(&Xin[(size_t)s2 * 128 + lane * 2]);
            unsigned u3 = *reinterpret_cast<const unsigned*>(&Xin[(size_t)s3 * 128 + lane * 2]);
            accx = fmaf(w0, blo(u0), accx); accy = fmaf(w0, bhi(u0), accy);
            accx = fmaf(w1, blo(u1), accx); accy = fmaf(w1, bhi(u1), accy);
            accx = fmaf(w2, blo(u2), accx); accy = fmaf(w2, bhi(u2), accy);
            accx = fmaf(w3, blo(u3), accx); accy = fmaf(w3, bhi(u3), accy);
        }
        for (; i < cnt; ++i) {
            int   s0 = __shfl(sv, i);
            float w0 = __shfl(wv, i);
            unsigned u0 = *reinterpret_cast<const unsigned*>(&Xin[(size_t)s0 * 128 + lane * 2]);
            accx = fmaf(w0, blo(u0), accx); accy = fmaf(w0, bhi(u0), accy);
        }
    }
    unsigned us = *reinterpret_cast<const unsigned*>(&Xin[(size_t)node * 128 + lane * 2]);
    accx += ALPHA * blo(us);
    accy += ALPHA * bhi(us);
    if (!FINAL) {
        unsigned short* out = (unsigned short*)outv;
        *reinterpret_cast<unsigned*>(&out[(size_t)node * 128 + lane * 2]) = cvtpk(accx, accy);
    } else {
        float* out = (float*)outv;
        int d = lane * 2;
        float* dst = (d < 64) ? &out[(size_t)node * 64 + d]
                              : &out[(size_t)NN * 64 + (size_t)node * 64 + (d - 64)];
        *reinterpret_cast<float2*>(dst) = make_float2(accx, accy);
    }
}

// ---------------------------------------------------------------------------
extern "C" void kernel_launch(void* const* d_in, const int* in_sizes, int n_in,
                              void* d_out, int out_size, void* d_ws, size_t ws_size,
                              hipStream_t stream)
{
    const int*   ei       = (const int*)d_in[0];
    const float* ew       = (const float*)d_in[1];
    const float* img_feat = (const float*)d_in[2];
    const float* txt_feat = (const float*)d_in[3];
    const float* img_w    = (const float*)d_in[4];
    const float* img_b    = (const float*)d_in[5];
    const float* txt_w    = (const float*)d_in[6];
    const float* txt_b    = (const float*)d_in[7];
    const float* img_pref = (const float*)d_in[8];
    const float* txt_pref = (const float*)d_in[9];
    float* out = (float*)d_out;

    const size_t XBYTES = (size_t)NN * 128 * 2;      // bf16
    char* ws = (char*)d_ws;
    size_t off = 0;
    auto alloc = [&](size_t bytes) -> void* {
        void* p = ws + off;
        off = (off + bytes + 255) & ~(size_t)255;
        return p;
    };
    unsigned short* Xa = (unsigned short*)alloc(XBYTES);
    unsigned short* Xb = (unsigned short*)alloc(XBYTES);
    int*   deg     = (int*)alloc((size_t)NN * 4);
    int*   row_ptr = (int*)alloc((size_t)(NN + 1) * 4);
    int*   cursor  = (int*)alloc((size_t)NN * 4);
    int2*  epk     = (int2*)alloc((size_t)N_EDGES * 8);
    int*   bsums   = (int*)alloc(256 * 4);
    short* WtImg   = (short*)alloc((size_t)2048 * 64 * 2);
    short* WtTxt   = (short*)alloc((size_t)384 * 64 * 2);

    hipMemsetAsync(deg, 0, (size_t)NN * 4, stream);

    prep<<<PREP_ALL, 256, 0, stream>>>(img_pref, txt_pref, Xa,
                                       img_w, WtImg, txt_w, WtTxt, ei, deg);

    scan1<<<137, 256, 0, stream>>>(deg, row_ptr, bsums);
    scan23<<<137, 256, 0, stream>>>(bsums, row_ptr, cursor);

    gemm_fill<<<1250 + 7813, 128, 0, stream>>>(img_feat, WtImg, img_b,
                                               txt_feat, WtTxt, txt_b, Xa,
                                               ei, ew, cursor, epk);

    propagate<false><<<35000, 256, 0, stream>>>(Xa, row_ptr, epk, Xb);
    propagate<true ><<<35000, 256, 0, stream>>>(Xb, row_ptr, epk, out);
}